// Round 1
// 891.052 us; speedup vs baseline: 1.1573x; 1.1573x over previous
//
#include <hip/hip_runtime.h>
#include <cstddef>

#define S 512
#define SHIFT_HW 18      // 512*512 = 1<<18
#define NCOL 16384

// workspace layout (float offsets). q/k/v are COLUMN-MAJOR blocked:
//   qb[bh][n][r], bh in [0,16), n in [0,16384), r in [0,96)
// so K1's stores (r contiguous) and K3/K5's tile loads (n-range contiguous)
// are both coalesced. Round-3 rocprof: row-major gave 2x WRITE_SIZE (partial
// line RMW) and capped K1 at 1.35 TB/s combined.
#define QB_OFF 0ull
#define KB_OFF 25165824ull
#define VB_OFF 50331648ull
#define G_OFF  75497472ull
#define SQ_OFF 75644928ull
#define SK_OFF 75646464ull
#define A_OFF  75648000ull

#define QS_STRIDE 327    // odd (7 mod 32): depthwise reads <=2-way bank aliasing

// ---------------------------------------------------------------------------
// K1 v4: fused 1x1 qkv conv + 3x3 depthwise (zero pad) + scatter to
// column-major blocked layout. grid (32,32,2), block 384. 16x16 tile.
// v4 change: 1x1-conv weights are staged per-group into double-buffered LDS
// (4.6 KB x2) and read via broadcast ds_read_b128. v3 streamed them as s_load
// chunks; 4 resident blocks at different group phases thrashed the 16 KB
// scalar L1, serializing every oc-pair on L2 latency (VALUBusy 34%, 65%
// stall). Staging is done by the otherwise-idle lanes t>=324 during the
// pointwise phase; the two existing barriers order write->read.
// ---------------------------------------------------------------------------
__global__ __launch_bounds__(384) void k1_qkv_dw(
    const float* __restrict__ x, const float* __restrict__ qkv_w,
    const float* __restrict__ dw_w,
    float* __restrict__ qb, float* __restrict__ kb, float* __restrict__ vb)
{
  const int t = threadIdx.x;
  const int b = blockIdx.z;
  const int W0 = blockIdx.x * 16, H0 = blockIdx.y * 16;
  __shared__ float qs[24 * QS_STRIDE];   // 24-ch group over 18x18 halo
  __shared__ float dws[1296];            // all depthwise weights (144 ch x 9)
  __shared__ float qws[2][1152];         // double-buffered 1x1 weights (24x48)

  for (int i = t; i < 1296; i += 384) dws[i] = dw_w[i];
  // prologue: stage group 0 weights
  for (int i = t; i < 288; i += 384)
    ((float4*)qws[0])[i] = ((const float4*)qkv_w)[i];

  // per-thread halo pixel, x channels held in registers across all 6 groups
  float xv[48];
  const int p  = t;
  const int hy = p / 18, hx = p % 18;            // valid for t<324
  const int Hg = H0 - 1 + hy, Wg = W0 - 1 + hx;
  const bool inb = (t < 324) && (Hg >= 0) && (Hg < S) && (Wg >= 0) && (Wg < S);
  const float* xb = x + ((size_t)b * 48 << SHIFT_HW) + (inb ? ((Hg << 9) + Wg) : 0);
  #pragma unroll
  for (int ic = 0; ic < 48; ++ic) {
    float v = 0.0f;
    if (inb) v = xb[(size_t)ic << SHIFT_HW];
    xv[ic] = v;
  }

  // depthwise task: thread owns (ch, output row y), all 16 x-positions
  const int ch = t >> 4;                 // 0..23 (channel within group)
  const int y  = t & 15;                 // output row within tile
  const int nb = (blockIdx.y * 4 + (y >> 2)) * 128 + blockIdx.x * 4;
  const float* qrow = qs + ch * QS_STRIDE + y * 18;  // halo rows y..y+2

  __syncthreads();   // dws + qws[0] ready

  #pragma unroll 1
  for (int g = 0; g < 6; ++g) {
    // ---- pointwise GEMM: 24 output channels for this group, halo pixels ----
    // weights from LDS, broadcast b128 reads (no scalar-cache traffic)
    if (t < 324) {
      const float* wgp = qws[g & 1];
      #pragma unroll
      for (int oc = 0; oc < 24; oc += 2) {
        float a0 = 0.f, a1 = 0.f;
        #pragma unroll
        for (int ic4 = 0; ic4 < 12; ++ic4) {
          const float4 w0 = *(const float4*)(wgp + oc * 48 + ic4 * 4);
          const float4 w1 = *(const float4*)(wgp + (oc + 1) * 48 + ic4 * 4);
          a0 += w0.x * xv[ic4 * 4 + 0] + w0.y * xv[ic4 * 4 + 1]
              + w0.z * xv[ic4 * 4 + 2] + w0.w * xv[ic4 * 4 + 3];
          a1 += w1.x * xv[ic4 * 4 + 0] + w1.y * xv[ic4 * 4 + 1]
              + w1.z * xv[ic4 * 4 + 2] + w1.w * xv[ic4 * 4 + 3];
        }
        qs[oc * QS_STRIDE + p]       = a0;
        qs[(oc + 1) * QS_STRIDE + p] = a1;
      }
    } else if (g < 5) {
      // idle lanes stage next group's weights into the other buffer.
      // qws[(g+1)&1] was last READ in pointwise(g-1); two barriers separate.
      float4* dstq = (float4*)qws[(g + 1) & 1];
      const float4* srcq = (const float4*)qkv_w + (g + 1) * 288;
      for (int i = t - 324; i < 288; i += 60) dstq[i] = srcq[i];
    }
    __syncthreads();

    // ---- depthwise 3x3 (sliding window) + coalesced float4 stores ----
    // out[xq] -> n = nb + (xq>>2), r = c*16 + (y&3)*4 + (xq&3):
    // one float4 per n, r contiguous. A wave's 16B pieces tile 128-256B
    // contiguous segments -> fully dirtied lines, no RMW.
    const int tensor = g >> 1;            // 0=q,1=k,2=v
    const int chbase = (g & 1) * 24;
    const int chg  = chbase + ch;         // channel within tensor
    const int head = chg / 6, c = chg - 6 * head;
    float* dst = (tensor == 0) ? qb : (tensor == 1) ? kb : vb;
    float* dstp = dst + (size_t)((b * 8 + head) * 16384 + nb) * 96
                      + c * 16 + (y & 3) * 4;
    const float* wp = dws + (tensor * 48 + chg) * 9;
    const float w0 = wp[0], w1 = wp[1], w2 = wp[2];
    const float w3 = wp[3], w4 = wp[4], w5 = wp[5];
    const float w6 = wp[6], w7 = wp[7], w8 = wp[8];

    float p00 = qrow[0], p01 = qrow[18], p02 = qrow[36];
    float p10 = qrow[1], p11 = qrow[19], p12 = qrow[37];
    #pragma unroll
    for (int wl = 0; wl < 4; ++wl) {
      float o[4];
      #pragma unroll
      for (int u = 0; u < 4; ++u) {
        const int xq = wl * 4 + u;
        const float n0 = qrow[xq + 2];
        const float n1 = qrow[xq + 20];
        const float n2 = qrow[xq + 38];
        o[u] = w0 * p00 + w1 * p10 + w2 * n0
             + w3 * p01 + w4 * p11 + w5 * n1
             + w6 * p02 + w7 * p12 + w8 * n2;
        p00 = p10; p01 = p11; p02 = p12;
        p10 = n0;  p11 = n1;  p12 = n2;
      }
      float4 v4 = {o[0], o[1], o[2], o[3]};
      *(float4*)(dstp + (size_t)wl * 96) = v4;
    }
    __syncthreads();
  }
}

// ---------------------------------------------------------------------------
// K3 v2: Gram G[bh] = q@k^T (96x96, K=16384) + row sum-squares. Column-major
// input: tile load is a flat contiguous copy. grid (64 x 256-col chunks, 16).
// ---------------------------------------------------------------------------
__global__ __launch_bounds__(256) void k3_gram(
    const float* __restrict__ qb, const float* __restrict__ kb,
    float* __restrict__ G, float* __restrict__ sq, float* __restrict__ sk)
{
  const int t  = threadIdx.x;
  const int bh = blockIdx.y;
  const int n0 = blockIdx.x * 256;
  __shared__ float qt[6144];   // [64 n][96 r] flat
  __shared__ float kt[6144];
  const int ti = t >> 4, tj = t & 15;
  float acc[6][6];
  #pragma unroll
  for (int r = 0; r < 6; ++r)
    #pragma unroll
    for (int s_ = 0; s_ < 6; ++s_) acc[r][s_] = 0.f;
  float ss = 0.f;
  const float* qbase = qb + (size_t)bh * 16384 * 96;
  const float* kbase = kb + (size_t)bh * 16384 * 96;

  #pragma unroll 1
  for (int st = 0; st < 4; ++st) {
    __syncthreads();
    const float4* qsrc = (const float4*)(qbase + (size_t)(n0 + st * 64) * 96);
    const float4* ksrc = (const float4*)(kbase + (size_t)(n0 + st * 64) * 96);
    #pragma unroll
    for (int r = 0; r < 6; ++r) {
      const int f4 = r * 256 + t;
      ((float4*)qt)[f4] = qsrc[f4];
      ((float4*)kt)[f4] = ksrc[f4];
    }
    __syncthreads();
    #pragma unroll 2
    for (int nn = 0; nn < 64; ++nn) {
      const float* qr = qt + nn * 96 + ti * 6;
      const float* kr = kt + nn * 96 + tj * 6;
      const float2 q0 = *(const float2*)(qr);
      const float2 q1 = *(const float2*)(qr + 2);
      const float2 q2 = *(const float2*)(qr + 4);
      const float2 k0 = *(const float2*)(kr);
      const float2 k1 = *(const float2*)(kr + 2);
      const float2 k2 = *(const float2*)(kr + 4);
      const float qv[6] = {q0.x, q0.y, q1.x, q1.y, q2.x, q2.y};
      const float kv[6] = {k0.x, k0.y, k1.x, k1.y, k2.x, k2.y};
      #pragma unroll
      for (int r = 0; r < 6; ++r)
        #pragma unroll
        for (int s_ = 0; s_ < 6; ++s_)
          acc[r][s_] += qv[r] * kv[s_];
    }
    if (t < 192) {                          // sum-squares for norms
      const float* base = (t < 96) ? qt : kt;
      const int srow = (t < 96) ? t : (t - 96);
      float s2 = 0.f;
      #pragma unroll 8
      for (int nn = 0; nn < 64; ++nn) {
        const float v = base[nn * 96 + srow];
        s2 += v * v;
      }
      ss += s2;
    }
  }
  float* Gb = G + (size_t)bh * 9216;
  #pragma unroll
  for (int r = 0; r < 6; ++r)
    #pragma unroll
    for (int s_ = 0; s_ < 6; ++s_)
      atomicAdd(Gb + (ti * 6 + r) * 96 + (tj * 6 + s_), acc[r][s_]);
  if (t < 96)       atomicAdd(sq + bh * 96 + t,        ss);
  else if (t < 192) atomicAdd(sk + bh * 96 + (t - 96), ss);
}

// ---------------------------------------------------------------------------
// K4: normalize logits + per-head temperature + row softmax (96 wide).
// grid (96 rows, 16 bh), block 128.
// ---------------------------------------------------------------------------
__global__ __launch_bounds__(128) void k4_softmax(
    const float* __restrict__ G, const float* __restrict__ sq,
    const float* __restrict__ sk, const float* __restrict__ temp,
    float* __restrict__ A)
{
  const int i  = blockIdx.x;
  const int bh = blockIdx.y;
  const int h  = bh & 7;
  const int t  = threadIdx.x;
  __shared__ float red[128];

  const float nq    = fmaxf(sqrtf(sq[bh * 96 + i]), 1e-12f);
  const float scale = temp[h] / nq;
  float logit = 0.f, val = -1e30f;
  if (t < 96) {
    const float nk = fmaxf(sqrtf(sk[bh * 96 + t]), 1e-12f);
    logit = G[(size_t)bh * 9216 + i * 96 + t] * scale / nk;
    val = logit;
  }
  red[t] = val; __syncthreads();
  #pragma unroll
  for (int o = 64; o > 0; o >>= 1) {
    if (t < o) red[t] = fmaxf(red[t], red[t + o]);
    __syncthreads();
  }
  const float m = red[0]; __syncthreads();
  const float e = (t < 96) ? __expf(logit - m) : 0.f;
  red[t] = e; __syncthreads();
  #pragma unroll
  for (int o = 64; o > 0; o >>= 1) {
    if (t < o) red[t] += red[t + o];
    __syncthreads();
  }
  const float ssum = red[0];
  if (t < 96) A[(size_t)bh * 9216 + i * 96 + t] = e / ssum;
}

// ---------------------------------------------------------------------------
// K5 v2: out = proj( from_blocks( A @ v ) ). One block = 16 attention cols.
// v loaded from column-major layout (coalesced); A@v result kept in regs so
// ao aliases vt -> 49 KB LDS -> 3 blocks/CU. grid (8,128,2), block 256.
// ---------------------------------------------------------------------------
__global__ __launch_bounds__(256) void k5_av_proj(
    const float* __restrict__ vb, const float* __restrict__ A,
    const float* __restrict__ pw, float* __restrict__ out)
{
  const int t  = threadIdx.x;
  const int wg = blockIdx.x, hh = blockIdx.y, b = blockIdx.z;
  const int n0 = hh * 128 + wg * 16;
  __shared__ float smem[12288];   // phase 0-1: vt[h][r][16 nl]; phase 2-3: ao

  // phase 0: load v tile. global: 16 segments of 64B per wave; LDS scatter
  // (16u+nl banks) is 4-way on a handful of insts (negligible).
  #pragma unroll
  for (int it = 0; it < 12; ++it) {
    const int i4  = it * 256 + t;          // [0, 3072)
    const int h   = i4 / 384;
    const int q   = i4 - h * 384;
    const int r4g = q >> 6;
    const int rem = q & 63;
    const int nl  = rem >> 2;
    const int r4  = r4g * 4 + (rem & 3);
    const float4 v = *(const float4*)(vb
        + (size_t)((b * 8 + h) * 16384 + n0 + nl) * 96 + r4 * 4);
    float* dl = smem + (h * 96 + r4 * 4) * 16 + nl;
    dl[0] = v.x; dl[16] = v.y; dl[32] = v.z; dl[48] = v.w;
  }
  __syncthreads();

  // phase 1: A @ v into registers (res). A rows as float4: 4x fewer loads.
  float4 res[6][2];
  #pragma unroll 1
  for (int r = 0; r < 6; ++r) {
    const int task = r * 256 + t;           // h(8) x ip(48) x n4(4)
    const int n4 = task & 3;
    const int ip = (task >> 2) % 48;
    const int h  = task / 192;
    const int i0 = ip * 2;
    const float* arow0 = A + (size_t)((b * 8 + h) * 96 + i0) * 96;
    const float* arow1 = arow0 + 96;
    const float* vp = smem + h * 1536 + n4 * 4;
    float4 a0 = {0, 0, 0, 0}, a1 = {0, 0, 0, 0};
    #pragma unroll 2
    for (int j4 = 0; j4 < 24; ++j4) {
      const float4 w0 = *(const float4*)(arow0 + j4 * 4);
      const float4 w1 = *(const float4*)(arow1 + j4 * 4);
      const float4 v0 = *(const float4*)(vp + (j4 * 4 + 0) * 16);
      const float4 v1 = *(const float4*)(vp + (j4 * 4 + 1) * 16);
      const float4 v2 = *(const float4*)(vp + (j4 * 4 + 2) * 16);
      const float4 v3 = *(const float4*)(vp + (j4 * 4 + 3) * 16);
      a0.x += w0.x * v0.x + w0.y * v1.x + w0.z * v2.x + w0.w * v3.x;
      a0.y += w0.x * v0.y + w0.y * v1.y + w0.z * v2.y + w0.w * v3.y;
      a0.z += w0.x * v0.z + w0.y * v1.z + w0.z * v2.z + w0.w * v3.z;
      a0.w += w0.x * v0.w + w0.y * v1.w + w0.z * v2.w + w0.w * v3.w;
      a1.x += w1.x * v0.x + w1.y * v1.x + w1.z * v2.x + w1.w * v3.x;
      a1.y += w1.x * v0.y + w1.y * v1.y + w1.z * v2.y + w1.w * v3.y;
      a1.z += w1.x * v0.z + w1.y * v1.z + w1.z * v2.z + w1.w * v3.z;
      a1.w += w1.x * v0.w + w1.y * v1.w + w1.z * v2.w + w1.w * v3.w;
    }
    res[r][0] = a0; res[r][1] = a1;
  }
  __syncthreads();   // all vt reads done; smem becomes ao

  // phase 2: write res into ao[ic][p][ww]
  #pragma unroll
  for (int r = 0; r < 6; ++r) {
    const int task = r * 256 + t;
    const int n4 = task & 3;
    const int ip = (task >> 2) % 48;
    const int h  = task / 192;
    const int i0 = ip * 2, i1 = i0 + 1;
    *(float4*)(smem + ((h * 6 + (i0 >> 4)) * 16 + (i0 & 15)) * 16 + n4 * 4) = res[r][0];
    *(float4*)(smem + ((h * 6 + (i1 >> 4)) * 16 + (i1 & 15)) * 16 + n4 * 4) = res[r][1];
  }
  __syncthreads();

  // phase 3: proj 1x1: thread owns one output pixel across 48 channels
  const int xl = t & 63, ph = t >> 6;
  const int p  = ph * 4 + (xl & 3);
  const int wwl = xl >> 2;
  float sv[48];
  #pragma unroll
  for (int ic = 0; ic < 48; ++ic) sv[ic] = smem[(ic * 16 + p) * 16 + wwl];
  const int H = hh * 4 + ph;
  const int Wp = wg * 64 + xl;
  float* outp = out + ((size_t)b * 48 << SHIFT_HW) + (H << 9) + Wp;
  #pragma unroll 1
  for (int oc = 0; oc < 48; oc += 2) {
    float acc0 = 0.f, acc1 = 0.f;
    #pragma unroll
    for (int ic = 0; ic < 48; ++ic) {
      acc0 += pw[oc * 48 + ic]       * sv[ic];   // uniform -> s_loads
      acc1 += pw[(oc + 1) * 48 + ic] * sv[ic];
    }
    outp[(size_t)oc << SHIFT_HW]       = acc0;
    outp[(size_t)(oc + 1) << SHIFT_HW] = acc1;
  }
}

// ---------------------------------------------------------------------------
extern "C" void kernel_launch(void* const* d_in, const int* in_sizes, int n_in,
                              void* d_out, int out_size, void* d_ws, size_t ws_size,
                              hipStream_t stream) {
  const float* x      = (const float*)d_in[0];
  const float* qkv_w  = (const float*)d_in[1];
  const float* dw_w   = (const float*)d_in[2];
  const float* proj_w = (const float*)d_in[3];
  const float* temp   = (const float*)d_in[4];
  float* ws = (float*)d_ws;
  float* qb = ws + QB_OFF;
  float* kb = ws + KB_OFF;
  float* vb = ws + VB_OFF;
  float* G  = ws + G_OFF;
  float* sq = ws + SQ_OFF;
  float* sk = ws + SK_OFF;
  float* A  = ws + A_OFF;

  // zero G + sq + sk (contiguous region); A is fully overwritten by k4
  hipMemsetAsync(G, 0, (size_t)(147456 + 3072) * sizeof(float), stream);

  k1_qkv_dw<<<dim3(32, 32, 2), 384, 0, stream>>>(x, qkv_w, dw_w, qb, kb, vb);
  k3_gram<<<dim3(64, 16), 256, 0, stream>>>(qb, kb, G, sq, sk);
  k4_softmax<<<dim3(96, 16), 128, 0, stream>>>(G, sq, sk, temp, A);
  k5_av_proj<<<dim3(8, 128, 2), 256, 0, stream>>>(vb, A, proj_w, (float*)d_out);
}

// Round 2
// 874.024 us; speedup vs baseline: 1.1798x; 1.0195x over previous
//
#include <hip/hip_runtime.h>
#include <cstddef>

#define S 512
#define SHIFT_HW 18      // 512*512 = 1<<18
#define NCOL 16384

// workspace layout (float offsets). q/k/v are COLUMN-MAJOR blocked:
//   qb[bh][n][r], bh in [0,16), n in [0,16384), r in [0,96)
// so K1's stores (r contiguous) and K3/K5's tile loads (n-range contiguous)
// are both coalesced. Round-3 rocprof: row-major gave 2x WRITE_SIZE (partial
// line RMW) and capped K1 at 1.35 TB/s combined.
#define QB_OFF 0ull
#define KB_OFF 25165824ull
#define VB_OFF 50331648ull
#define G_OFF  75497472ull
#define SQ_OFF 75644928ull
#define SK_OFF 75646464ull
#define A_OFF  75648000ull

#define QS_STRIDE 327    // odd (7 mod 32): depthwise reads <=2-way bank aliasing

// ---------------------------------------------------------------------------
// K1 v5: fused 1x1 qkv conv + 3x3 depthwise (zero pad) + scatter to
// column-major blocked layout. grid (32,32,2), block 384. 16x16 tile.
// v4: 1x1 weights double-buffered in LDS (broadcast b128 reads) -- fixed
// scalar-L1 thrash, VALUBusy 34->57%.
// v5: __launch_bounds__(384,4). v4 compiled to 56 VGPR (default heuristic
// targets 8 waves/SIMD) while LDS (46 KB -> 3 blocks/CU = 4.5 waves/SIMD)
// already caps occupancy -> xv[48] was spilled to scratch and re-read every
// group (43% stall). min-4-waves/EU raises the cap to 128 VGPR so xv stays
// resident.
// ---------------------------------------------------------------------------
__global__ __launch_bounds__(384, 4) void k1_qkv_dw(
    const float* __restrict__ x, const float* __restrict__ qkv_w,
    const float* __restrict__ dw_w,
    float* __restrict__ qb, float* __restrict__ kb, float* __restrict__ vb)
{
  const int t = threadIdx.x;
  const int b = blockIdx.z;
  const int W0 = blockIdx.x * 16, H0 = blockIdx.y * 16;
  __shared__ float qs[24 * QS_STRIDE];   // 24-ch group over 18x18 halo
  __shared__ float dws[1296];            // all depthwise weights (144 ch x 9)
  __shared__ float qws[2][1152];         // double-buffered 1x1 weights (24x48)

  for (int i = t; i < 1296; i += 384) dws[i] = dw_w[i];
  // prologue: stage group 0 weights
  for (int i = t; i < 288; i += 384)
    ((float4*)qws[0])[i] = ((const float4*)qkv_w)[i];

  // per-thread halo pixel, x channels held in registers across all 6 groups
  float xv[48];
  const int p  = t;
  const int hy = p / 18, hx = p % 18;            // valid for t<324
  const int Hg = H0 - 1 + hy, Wg = W0 - 1 + hx;
  const bool inb = (t < 324) && (Hg >= 0) && (Hg < S) && (Wg >= 0) && (Wg < S);
  const float* xb = x + ((size_t)b * 48 << SHIFT_HW) + (inb ? ((Hg << 9) + Wg) : 0);
  #pragma unroll
  for (int ic = 0; ic < 48; ++ic) {
    float v = 0.0f;
    if (inb) v = xb[(size_t)ic << SHIFT_HW];
    xv[ic] = v;
  }

  // depthwise task: thread owns (ch, output row y), all 16 x-positions
  const int ch = t >> 4;                 // 0..23 (channel within group)
  const int y  = t & 15;                 // output row within tile
  const int nb = (blockIdx.y * 4 + (y >> 2)) * 128 + blockIdx.x * 4;
  const float* qrow = qs + ch * QS_STRIDE + y * 18;  // halo rows y..y+2

  __syncthreads();   // dws + qws[0] ready

  #pragma unroll 1
  for (int g = 0; g < 6; ++g) {
    // ---- pointwise GEMM: 24 output channels for this group, halo pixels ----
    // weights from LDS, broadcast b128 reads (no scalar-cache traffic)
    if (t < 324) {
      const float* wgp = qws[g & 1];
      #pragma unroll
      for (int oc = 0; oc < 24; oc += 2) {
        float a0 = 0.f, a1 = 0.f;
        #pragma unroll
        for (int ic4 = 0; ic4 < 12; ++ic4) {
          const float4 w0 = *(const float4*)(wgp + oc * 48 + ic4 * 4);
          const float4 w1 = *(const float4*)(wgp + (oc + 1) * 48 + ic4 * 4);
          a0 += w0.x * xv[ic4 * 4 + 0] + w0.y * xv[ic4 * 4 + 1]
              + w0.z * xv[ic4 * 4 + 2] + w0.w * xv[ic4 * 4 + 3];
          a1 += w1.x * xv[ic4 * 4 + 0] + w1.y * xv[ic4 * 4 + 1]
              + w1.z * xv[ic4 * 4 + 2] + w1.w * xv[ic4 * 4 + 3];
        }
        qs[oc * QS_STRIDE + p]       = a0;
        qs[(oc + 1) * QS_STRIDE + p] = a1;
      }
    } else if (g < 5) {
      // idle lanes stage next group's weights into the other buffer.
      // qws[(g+1)&1] was last READ in pointwise(g-1); two barriers separate.
      float4* dstq = (float4*)qws[(g + 1) & 1];
      const float4* srcq = (const float4*)qkv_w + (g + 1) * 288;
      for (int i = t - 324; i < 288; i += 60) dstq[i] = srcq[i];
    }
    __syncthreads();

    // ---- depthwise 3x3 (sliding window) + coalesced float4 stores ----
    // out[xq] -> n = nb + (xq>>2), r = c*16 + (y&3)*4 + (xq&3):
    // one float4 per n, r contiguous. A wave's 16B pieces tile 128-256B
    // contiguous segments -> fully dirtied lines, no RMW.
    const int tensor = g >> 1;            // 0=q,1=k,2=v
    const int chbase = (g & 1) * 24;
    const int chg  = chbase + ch;         // channel within tensor
    const int head = chg / 6, c = chg - 6 * head;
    float* dst = (tensor == 0) ? qb : (tensor == 1) ? kb : vb;
    float* dstp = dst + (size_t)((b * 8 + head) * 16384 + nb) * 96
                      + c * 16 + (y & 3) * 4;
    const float* wp = dws + (tensor * 48 + chg) * 9;
    const float w0 = wp[0], w1 = wp[1], w2 = wp[2];
    const float w3 = wp[3], w4 = wp[4], w5 = wp[5];
    const float w6 = wp[6], w7 = wp[7], w8 = wp[8];

    float p00 = qrow[0], p01 = qrow[18], p02 = qrow[36];
    float p10 = qrow[1], p11 = qrow[19], p12 = qrow[37];
    #pragma unroll
    for (int wl = 0; wl < 4; ++wl) {
      float o[4];
      #pragma unroll
      for (int u = 0; u < 4; ++u) {
        const int xq = wl * 4 + u;
        const float n0 = qrow[xq + 2];
        const float n1 = qrow[xq + 20];
        const float n2 = qrow[xq + 38];
        o[u] = w0 * p00 + w1 * p10 + w2 * n0
             + w3 * p01 + w4 * p11 + w5 * n1
             + w6 * p02 + w7 * p12 + w8 * n2;
        p00 = p10; p01 = p11; p02 = p12;
        p10 = n0;  p11 = n1;  p12 = n2;
      }
      float4 v4 = {o[0], o[1], o[2], o[3]};
      *(float4*)(dstp + (size_t)wl * 96) = v4;
    }
    __syncthreads();
  }
}

// ---------------------------------------------------------------------------
// K3 v3: Gram G[bh] = q@k^T (96x96, K=16384) + row sum-squares. Column-major
// input: tile load is a flat contiguous copy. grid (64 x 256-col chunks, 16).
// v3: __launch_bounds__(256,3) -- acc[6][6]+qv/kv+addr is ~65 live floats;
// the default 64-VGPR cap (targeting 8 waves/SIMD that 48 KB LDS forbids
// anyway: 3 blocks/CU = 3 waves/SIMD) forced spills. Cap now ~168.
// ---------------------------------------------------------------------------
__global__ __launch_bounds__(256, 3) void k3_gram(
    const float* __restrict__ qb, const float* __restrict__ kb,
    float* __restrict__ G, float* __restrict__ sq, float* __restrict__ sk)
{
  const int t  = threadIdx.x;
  const int bh = blockIdx.y;
  const int n0 = blockIdx.x * 256;
  __shared__ float qt[6144];   // [64 n][96 r] flat
  __shared__ float kt[6144];
  const int ti = t >> 4, tj = t & 15;
  float acc[6][6];
  #pragma unroll
  for (int r = 0; r < 6; ++r)
    #pragma unroll
    for (int s_ = 0; s_ < 6; ++s_) acc[r][s_] = 0.f;
  float ss = 0.f;
  const float* qbase = qb + (size_t)bh * 16384 * 96;
  const float* kbase = kb + (size_t)bh * 16384 * 96;

  #pragma unroll 1
  for (int st = 0; st < 4; ++st) {
    __syncthreads();
    const float4* qsrc = (const float4*)(qbase + (size_t)(n0 + st * 64) * 96);
    const float4* ksrc = (const float4*)(kbase + (size_t)(n0 + st * 64) * 96);
    #pragma unroll
    for (int r = 0; r < 6; ++r) {
      const int f4 = r * 256 + t;
      ((float4*)qt)[f4] = qsrc[f4];
      ((float4*)kt)[f4] = ksrc[f4];
    }
    __syncthreads();
    #pragma unroll 2
    for (int nn = 0; nn < 64; ++nn) {
      const float* qr = qt + nn * 96 + ti * 6;
      const float* kr = kt + nn * 96 + tj * 6;
      const float2 q0 = *(const float2*)(qr);
      const float2 q1 = *(const float2*)(qr + 2);
      const float2 q2 = *(const float2*)(qr + 4);
      const float2 k0 = *(const float2*)(kr);
      const float2 k1 = *(const float2*)(kr + 2);
      const float2 k2 = *(const float2*)(kr + 4);
      const float qv[6] = {q0.x, q0.y, q1.x, q1.y, q2.x, q2.y};
      const float kv[6] = {k0.x, k0.y, k1.x, k1.y, k2.x, k2.y};
      #pragma unroll
      for (int r = 0; r < 6; ++r)
        #pragma unroll
        for (int s_ = 0; s_ < 6; ++s_)
          acc[r][s_] += qv[r] * kv[s_];
    }
    if (t < 192) {                          // sum-squares for norms
      const float* base = (t < 96) ? qt : kt;
      const int srow = (t < 96) ? t : (t - 96);
      float s2 = 0.f;
      #pragma unroll 8
      for (int nn = 0; nn < 64; ++nn) {
        const float v = base[nn * 96 + srow];
        s2 += v * v;
      }
      ss += s2;
    }
  }
  float* Gb = G + (size_t)bh * 9216;
  #pragma unroll
  for (int r = 0; r < 6; ++r)
    #pragma unroll
    for (int s_ = 0; s_ < 6; ++s_)
      atomicAdd(Gb + (ti * 6 + r) * 96 + (tj * 6 + s_), acc[r][s_]);
  if (t < 96)       atomicAdd(sq + bh * 96 + t,        ss);
  else if (t < 192) atomicAdd(sk + bh * 96 + (t - 96), ss);
}

// ---------------------------------------------------------------------------
// K4: normalize logits + per-head temperature + row softmax (96 wide).
// grid (96 rows, 16 bh), block 128.
// ---------------------------------------------------------------------------
__global__ __launch_bounds__(128) void k4_softmax(
    const float* __restrict__ G, const float* __restrict__ sq,
    const float* __restrict__ sk, const float* __restrict__ temp,
    float* __restrict__ A)
{
  const int i  = blockIdx.x;
  const int bh = blockIdx.y;
  const int h  = bh & 7;
  const int t  = threadIdx.x;
  __shared__ float red[128];

  const float nq    = fmaxf(sqrtf(sq[bh * 96 + i]), 1e-12f);
  const float scale = temp[h] / nq;
  float logit = 0.f, val = -1e30f;
  if (t < 96) {
    const float nk = fmaxf(sqrtf(sk[bh * 96 + t]), 1e-12f);
    logit = G[(size_t)bh * 9216 + i * 96 + t] * scale / nk;
    val = logit;
  }
  red[t] = val; __syncthreads();
  #pragma unroll
  for (int o = 64; o > 0; o >>= 1) {
    if (t < o) red[t] = fmaxf(red[t], red[t + o]);
    __syncthreads();
  }
  const float m = red[0]; __syncthreads();
  const float e = (t < 96) ? __expf(logit - m) : 0.f;
  red[t] = e; __syncthreads();
  #pragma unroll
  for (int o = 64; o > 0; o >>= 1) {
    if (t < o) red[t] += red[t + o];
    __syncthreads();
  }
  const float ssum = red[0];
  if (t < 96) A[(size_t)bh * 9216 + i * 96 + t] = e / ssum;
}

// ---------------------------------------------------------------------------
// K5 v3: out = proj( from_blocks( A @ v ) ). One block = 16 attention cols.
// v loaded from column-major layout (coalesced); A@v result kept in regs so
// ao aliases vt -> 49 KB LDS -> 3 blocks/CU. grid (8,128,2), block 256.
// v3: __launch_bounds__(256,3) -- res[6][2] (48 floats) + phase-1 float4
// temps and phase-3 sv[48] exceed the default 64-VGPR cap (8-waves/SIMD
// target that 48 KB LDS forbids); raising cap to ~168 keeps both in regs.
// ---------------------------------------------------------------------------
__global__ __launch_bounds__(256, 3) void k5_av_proj(
    const float* __restrict__ vb, const float* __restrict__ A,
    const float* __restrict__ pw, float* __restrict__ out)
{
  const int t  = threadIdx.x;
  const int wg = blockIdx.x, hh = blockIdx.y, b = blockIdx.z;
  const int n0 = hh * 128 + wg * 16;
  __shared__ float smem[12288];   // phase 0-1: vt[h][r][16 nl]; phase 2-3: ao

  // phase 0: load v tile. global: 16 segments of 64B per wave; LDS scatter
  // (16u+nl banks) is 4-way on a handful of insts (negligible).
  #pragma unroll
  for (int it = 0; it < 12; ++it) {
    const int i4  = it * 256 + t;          // [0, 3072)
    const int h   = i4 / 384;
    const int q   = i4 - h * 384;
    const int r4g = q >> 6;
    const int rem = q & 63;
    const int nl  = rem >> 2;
    const int r4  = r4g * 4 + (rem & 3);
    const float4 v = *(const float4*)(vb
        + (size_t)((b * 8 + h) * 16384 + n0 + nl) * 96 + r4 * 4);
    float* dl = smem + (h * 96 + r4 * 4) * 16 + nl;
    dl[0] = v.x; dl[16] = v.y; dl[32] = v.z; dl[48] = v.w;
  }
  __syncthreads();

  // phase 1: A @ v into registers (res). A rows as float4: 4x fewer loads.
  float4 res[6][2];
  #pragma unroll 1
  for (int r = 0; r < 6; ++r) {
    const int task = r * 256 + t;           // h(8) x ip(48) x n4(4)
    const int n4 = task & 3;
    const int ip = (task >> 2) % 48;
    const int h  = task / 192;
    const int i0 = ip * 2;
    const float* arow0 = A + (size_t)((b * 8 + h) * 96 + i0) * 96;
    const float* arow1 = arow0 + 96;
    const float* vp = smem + h * 1536 + n4 * 4;
    float4 a0 = {0, 0, 0, 0}, a1 = {0, 0, 0, 0};
    #pragma unroll 2
    for (int j4 = 0; j4 < 24; ++j4) {
      const float4 w0 = *(const float4*)(arow0 + j4 * 4);
      const float4 w1 = *(const float4*)(arow1 + j4 * 4);
      const float4 v0 = *(const float4*)(vp + (j4 * 4 + 0) * 16);
      const float4 v1 = *(const float4*)(vp + (j4 * 4 + 1) * 16);
      const float4 v2 = *(const float4*)(vp + (j4 * 4 + 2) * 16);
      const float4 v3 = *(const float4*)(vp + (j4 * 4 + 3) * 16);
      a0.x += w0.x * v0.x + w0.y * v1.x + w0.z * v2.x + w0.w * v3.x;
      a0.y += w0.x * v0.y + w0.y * v1.y + w0.z * v2.y + w0.w * v3.y;
      a0.z += w0.x * v0.z + w0.y * v1.z + w0.z * v2.z + w0.w * v3.z;
      a0.w += w0.x * v0.w + w0.y * v1.w + w0.z * v2.w + w0.w * v3.w;
      a1.x += w1.x * v0.x + w1.y * v1.x + w1.z * v2.x + w1.w * v3.x;
      a1.y += w1.x * v0.y + w1.y * v1.y + w1.z * v2.y + w1.w * v3.y;
      a1.z += w1.x * v0.z + w1.y * v1.z + w1.z * v2.z + w1.w * v3.z;
      a1.w += w1.x * v0.w + w1.y * v1.w + w1.z * v2.w + w1.w * v3.w;
    }
    res[r][0] = a0; res[r][1] = a1;
  }
  __syncthreads();   // all vt reads done; smem becomes ao

  // phase 2: write res into ao[ic][p][ww]
  #pragma unroll
  for (int r = 0; r < 6; ++r) {
    const int task = r * 256 + t;
    const int n4 = task & 3;
    const int ip = (task >> 2) % 48;
    const int h  = task / 192;
    const int i0 = ip * 2, i1 = i0 + 1;
    *(float4*)(smem + ((h * 6 + (i0 >> 4)) * 16 + (i0 & 15)) * 16 + n4 * 4) = res[r][0];
    *(float4*)(smem + ((h * 6 + (i1 >> 4)) * 16 + (i1 & 15)) * 16 + n4 * 4) = res[r][1];
  }
  __syncthreads();

  // phase 3: proj 1x1: thread owns one output pixel across 48 channels
  const int xl = t & 63, ph = t >> 6;
  const int p  = ph * 4 + (xl & 3);
  const int wwl = xl >> 2;
  float sv[48];
  #pragma unroll
  for (int ic = 0; ic < 48; ++ic) sv[ic] = smem[(ic * 16 + p) * 16 + wwl];
  const int H = hh * 4 + ph;
  const int Wp = wg * 64 + xl;
  float* outp = out + ((size_t)b * 48 << SHIFT_HW) + (H << 9) + Wp;
  #pragma unroll 1
  for (int oc = 0; oc < 48; oc += 2) {
    float acc0 = 0.f, acc1 = 0.f;
    #pragma unroll
    for (int ic = 0; ic < 48; ++ic) {
      acc0 += pw[oc * 48 + ic]       * sv[ic];   // uniform -> s_loads
      acc1 += pw[(oc + 1) * 48 + ic] * sv[ic];
    }
    outp[(size_t)oc << SHIFT_HW]       = acc0;
    outp[(size_t)(oc + 1) << SHIFT_HW] = acc1;
  }
}

// ---------------------------------------------------------------------------
extern "C" void kernel_launch(void* const* d_in, const int* in_sizes, int n_in,
                              void* d_out, int out_size, void* d_ws, size_t ws_size,
                              hipStream_t stream) {
  const float* x      = (const float*)d_in[0];
  const float* qkv_w  = (const float*)d_in[1];
  const float* dw_w   = (const float*)d_in[2];
  const float* proj_w = (const float*)d_in[3];
  const float* temp   = (const float*)d_in[4];
  float* ws = (float*)d_ws;
  float* qb = ws + QB_OFF;
  float* kb = ws + KB_OFF;
  float* vb = ws + VB_OFF;
  float* G  = ws + G_OFF;
  float* sq = ws + SQ_OFF;
  float* sk = ws + SK_OFF;
  float* A  = ws + A_OFF;

  // zero G + sq + sk (contiguous region); A is fully overwritten by k4
  hipMemsetAsync(G, 0, (size_t)(147456 + 3072) * sizeof(float), stream);

  k1_qkv_dw<<<dim3(32, 32, 2), 384, 0, stream>>>(x, qkv_w, dw_w, qb, kb, vb);
  k3_gram<<<dim3(64, 16), 256, 0, stream>>>(qb, kb, G, sq, sk);
  k4_softmax<<<dim3(96, 16), 128, 0, stream>>>(G, sq, sk, temp, A);
  k5_av_proj<<<dim3(8, 128, 2), 256, 0, stream>>>(vb, A, proj_w, (float*)d_out);
}

// Round 3
// 829.052 us; speedup vs baseline: 1.2438x; 1.0542x over previous
//
#include <hip/hip_runtime.h>
#include <cstddef>

#define S 512
#define SHIFT_HW 18      // 512*512 = 1<<18
#define NCOL 16384

// workspace layout (float offsets). q/k/v are COLUMN-MAJOR blocked:
//   qb[bh][n][r], bh in [0,16), n in [0,16384), r in [0,96)
// so K1's stores (r contiguous) and K3/K5's tile loads (n-range contiguous)
// are both coalesced. Row-major gave 2x WRITE_SIZE (partial line RMW).
#define QB_OFF 0ull
#define KB_OFF 25165824ull
#define VB_OFF 50331648ull
#define G_OFF  75497472ull
#define SQ_OFF 75644928ull
#define SK_OFF 75646464ull
#define A_OFF  75648000ull

#define QS_STRIDE 327    // odd (7 mod 32): depthwise reads <=2-way bank aliasing

// ---------------------------------------------------------------------------
// K1 v6: fused 1x1 qkv conv + 3x3 depthwise (zero pad) + scatter to
// column-major blocked layout. grid (32,32,2), block 384. 16x16 tile.
// v4: 1x1 weights double-buffered in LDS (broadcast b128) - VALUBusy 34->57%.
// v5: launch_bounds min-waves arg -- no effect (VGPR stayed 56, no spills).
// v6: pointwise register-tiled 2 pixels x 12 ocs per thread. v5 read the
// full 24x48 weight block per thread per group (288 ds_read_b128); broadcast
// does NOT dedupe LDS return bandwidth (64 lanes x 16B = 1KB/instr), so K1
// moved 18.3 GB through LDS = 265us at the 69 TB/s ceiling -- the real cap
// (VALUBusy 57%, LDS pipe ~76%). 2px/thread halves weight bytes per FMA.
// Per-output fp32 sum order identical to v5. xv grows to 96 regs ->
// launch_bounds(384,3) (cap 168) to guarantee no spill.
// ---------------------------------------------------------------------------
__global__ __launch_bounds__(384, 3) void k1_qkv_dw(
    const float* __restrict__ x, const float* __restrict__ qkv_w,
    const float* __restrict__ dw_w,
    float* __restrict__ qb, float* __restrict__ kb, float* __restrict__ vb)
{
  const int t = threadIdx.x;
  const int b = blockIdx.z;
  const int W0 = blockIdx.x * 16, H0 = blockIdx.y * 16;
  __shared__ float qs[24 * QS_STRIDE];   // 24-ch group over 18x18 halo
  __shared__ float dws[1296];            // all depthwise weights (144 ch x 9)
  __shared__ float qws[2][1152];         // double-buffered 1x1 weights (24x48)

  for (int i = t; i < 1296; i += 384) dws[i] = dw_w[i];
  // prologue: stage group 0 weights
  for (int i = t; i < 288; i += 384)
    ((float4*)qws[0])[i] = ((const float4*)qkv_w)[i];

  // pointwise task: thread owns pixel pair (p0,p1) and one 12-oc half.
  // adjacent lanes (t, t^1) load the same 2 pixels -> dup loads are L1 hits.
  const bool act = (t < 324);
  const int p0 = t & ~1, p1 = p0 + 1;    // even pixel + neighbor (same row:
  const int hy = p0 / 18, hx0 = p0 % 18; //  row width 18 is even)
  const int oh = t & 1;
  const int Hg  = H0 - 1 + hy;
  const int Wg0 = W0 - 1 + hx0, Wg1 = Wg0 + 1;
  const bool inb0 = act && (Hg >= 0) && (Hg < S) && (Wg0 >= 0) && (Wg0 < S);
  const bool inb1 = act && (Hg >= 0) && (Hg < S) && (Wg1 < S); // Wg1>=1>0
  const float* xb0 = x + ((size_t)b * 48 << SHIFT_HW) + (inb0 ? ((Hg << 9) + Wg0) : 0);
  const float* xb1 = x + ((size_t)b * 48 << SHIFT_HW) + (inb1 ? ((Hg << 9) + Wg1) : 0);
  float xv0[48], xv1[48];
  #pragma unroll
  for (int ic = 0; ic < 48; ++ic) {
    xv0[ic] = inb0 ? xb0[(size_t)ic << SHIFT_HW] : 0.0f;
    xv1[ic] = inb1 ? xb1[(size_t)ic << SHIFT_HW] : 0.0f;
  }

  // depthwise task: thread owns (ch, output row y), all 16 x-positions
  const int ch = t >> 4;                 // 0..23 (channel within group)
  const int y  = t & 15;                 // output row within tile
  const int nb = (blockIdx.y * 4 + (y >> 2)) * 128 + blockIdx.x * 4;
  const float* qrow = qs + ch * QS_STRIDE + y * 18;  // halo rows y..y+2

  __syncthreads();   // dws + qws[0] ready

  #pragma unroll 1
  for (int g = 0; g < 6; ++g) {
    // ---- pointwise GEMM: 2 pixels x 12 ocs per thread, weights from LDS ----
    if (act) {
      const float* wgp = qws[g & 1] + oh * 12 * 48;
      #pragma unroll
      for (int oc = 0; oc < 12; ++oc) {
        float a0 = 0.f, a1 = 0.f;
        const float* wr = wgp + oc * 48;
        #pragma unroll
        for (int ic4 = 0; ic4 < 12; ++ic4) {
          const float4 w = *(const float4*)(wr + ic4 * 4);
          a0 += w.x * xv0[ic4 * 4 + 0] + w.y * xv0[ic4 * 4 + 1]
              + w.z * xv0[ic4 * 4 + 2] + w.w * xv0[ic4 * 4 + 3];
          a1 += w.x * xv1[ic4 * 4 + 0] + w.y * xv1[ic4 * 4 + 1]
              + w.z * xv1[ic4 * 4 + 2] + w.w * xv1[ic4 * 4 + 3];
        }
        const int ocg = oh * 12 + oc;
        qs[ocg * QS_STRIDE + p0] = a0;
        qs[ocg * QS_STRIDE + p1] = a1;
      }
    } else if (g < 5) {
      // idle lanes stage next group's weights into the other buffer.
      // qws[(g+1)&1] was last READ in pointwise(g-1); two barriers separate.
      float4* dstq = (float4*)qws[(g + 1) & 1];
      const float4* srcq = (const float4*)qkv_w + (g + 1) * 288;
      for (int i = t - 324; i < 288; i += 60) dstq[i] = srcq[i];
    }
    __syncthreads();

    // ---- depthwise 3x3 (sliding window) + coalesced float4 stores ----
    // out[xq] -> n = nb + (xq>>2), r = c*16 + (y&3)*4 + (xq&3):
    // one float4 per n, r contiguous. A wave's 16B pieces tile 128-256B
    // contiguous segments -> fully dirtied lines, no RMW.
    const int tensor = g >> 1;            // 0=q,1=k,2=v
    const int chbase = (g & 1) * 24;
    const int chg  = chbase + ch;         // channel within tensor
    const int head = chg / 6, c = chg - 6 * head;
    float* dst = (tensor == 0) ? qb : (tensor == 1) ? kb : vb;
    float* dstp = dst + (size_t)((b * 8 + head) * 16384 + nb) * 96
                      + c * 16 + (y & 3) * 4;
    const float* wp = dws + (tensor * 48 + chg) * 9;
    const float w0 = wp[0], w1 = wp[1], w2 = wp[2];
    const float w3 = wp[3], w4 = wp[4], w5 = wp[5];
    const float w6 = wp[6], w7 = wp[7], w8 = wp[8];

    float p00 = qrow[0], p01 = qrow[18], p02 = qrow[36];
    float p10 = qrow[1], p11 = qrow[19], p12 = qrow[37];
    #pragma unroll
    for (int wl = 0; wl < 4; ++wl) {
      float o[4];
      #pragma unroll
      for (int u = 0; u < 4; ++u) {
        const int xq = wl * 4 + u;
        const float n0 = qrow[xq + 2];
        const float n1 = qrow[xq + 20];
        const float n2 = qrow[xq + 38];
        o[u] = w0 * p00 + w1 * p10 + w2 * n0
             + w3 * p01 + w4 * p11 + w5 * n1
             + w6 * p02 + w7 * p12 + w8 * n2;
        p00 = p10; p01 = p11; p02 = p12;
        p10 = n0;  p11 = n1;  p12 = n2;
      }
      float4 v4 = {o[0], o[1], o[2], o[3]};
      *(float4*)(dstp + (size_t)wl * 96) = v4;
    }
    __syncthreads();
  }
}

// ---------------------------------------------------------------------------
// K3 v4: Gram G[bh] = q@k^T (96x96, K=16384) + row sum-squares. Column-major
// input: tile load is a flat contiguous copy.
// v4: grid (64,16)->(32,16): 512-col chunks, 8 stages. Halves device-scope
// f32 atomic traffic to the 147KB G region (9.4M -> 4.7M ops); still 2
// blocks/CU (512 blocks).
// ---------------------------------------------------------------------------
__global__ __launch_bounds__(256, 3) void k3_gram(
    const float* __restrict__ qb, const float* __restrict__ kb,
    float* __restrict__ G, float* __restrict__ sq, float* __restrict__ sk)
{
  const int t  = threadIdx.x;
  const int bh = blockIdx.y;
  const int n0 = blockIdx.x * 512;
  __shared__ float qt[6144];   // [64 n][96 r] flat
  __shared__ float kt[6144];
  const int ti = t >> 4, tj = t & 15;
  float acc[6][6];
  #pragma unroll
  for (int r = 0; r < 6; ++r)
    #pragma unroll
    for (int s_ = 0; s_ < 6; ++s_) acc[r][s_] = 0.f;
  float ss = 0.f;
  const float* qbase = qb + (size_t)bh * 16384 * 96;
  const float* kbase = kb + (size_t)bh * 16384 * 96;

  #pragma unroll 1
  for (int st = 0; st < 8; ++st) {
    __syncthreads();
    const float4* qsrc = (const float4*)(qbase + (size_t)(n0 + st * 64) * 96);
    const float4* ksrc = (const float4*)(kbase + (size_t)(n0 + st * 64) * 96);
    #pragma unroll
    for (int r = 0; r < 6; ++r) {
      const int f4 = r * 256 + t;
      ((float4*)qt)[f4] = qsrc[f4];
      ((float4*)kt)[f4] = ksrc[f4];
    }
    __syncthreads();
    #pragma unroll 2
    for (int nn = 0; nn < 64; ++nn) {
      const float* qr = qt + nn * 96 + ti * 6;
      const float* kr = kt + nn * 96 + tj * 6;
      const float2 q0 = *(const float2*)(qr);
      const float2 q1 = *(const float2*)(qr + 2);
      const float2 q2 = *(const float2*)(qr + 4);
      const float2 k0 = *(const float2*)(kr);
      const float2 k1 = *(const float2*)(kr + 2);
      const float2 k2 = *(const float2*)(kr + 4);
      const float qv[6] = {q0.x, q0.y, q1.x, q1.y, q2.x, q2.y};
      const float kv[6] = {k0.x, k0.y, k1.x, k1.y, k2.x, k2.y};
      #pragma unroll
      for (int r = 0; r < 6; ++r)
        #pragma unroll
        for (int s_ = 0; s_ < 6; ++s_)
          acc[r][s_] += qv[r] * kv[s_];
    }
    if (t < 192) {                          // sum-squares for norms
      const float* base = (t < 96) ? qt : kt;
      const int srow = (t < 96) ? t : (t - 96);
      float s2 = 0.f;
      #pragma unroll 8
      for (int nn = 0; nn < 64; ++nn) {
        const float v = base[nn * 96 + srow];
        s2 += v * v;
      }
      ss += s2;
    }
  }
  float* Gb = G + (size_t)bh * 9216;
  #pragma unroll
  for (int r = 0; r < 6; ++r)
    #pragma unroll
    for (int s_ = 0; s_ < 6; ++s_)
      atomicAdd(Gb + (ti * 6 + r) * 96 + (tj * 6 + s_), acc[r][s_]);
  if (t < 96)       atomicAdd(sq + bh * 96 + t,        ss);
  else if (t < 192) atomicAdd(sk + bh * 96 + (t - 96), ss);
}

// ---------------------------------------------------------------------------
// K4: normalize logits + per-head temperature + row softmax (96 wide).
// grid (96 rows, 16 bh), block 128.
// ---------------------------------------------------------------------------
__global__ __launch_bounds__(128) void k4_softmax(
    const float* __restrict__ G, const float* __restrict__ sq,
    const float* __restrict__ sk, const float* __restrict__ temp,
    float* __restrict__ A)
{
  const int i  = blockIdx.x;
  const int bh = blockIdx.y;
  const int h  = bh & 7;
  const int t  = threadIdx.x;
  __shared__ float red[128];

  const float nq    = fmaxf(sqrtf(sq[bh * 96 + i]), 1e-12f);
  const float scale = temp[h] / nq;
  float logit = 0.f, val = -1e30f;
  if (t < 96) {
    const float nk = fmaxf(sqrtf(sk[bh * 96 + t]), 1e-12f);
    logit = G[(size_t)bh * 9216 + i * 96 + t] * scale / nk;
    val = logit;
  }
  red[t] = val; __syncthreads();
  #pragma unroll
  for (int o = 64; o > 0; o >>= 1) {
    if (t < o) red[t] = fmaxf(red[t], red[t + o]);
    __syncthreads();
  }
  const float m = red[0]; __syncthreads();
  const float e = (t < 96) ? __expf(logit - m) : 0.f;
  red[t] = e; __syncthreads();
  #pragma unroll
  for (int o = 64; o > 0; o >>= 1) {
    if (t < o) red[t] += red[t + o];
    __syncthreads();
  }
  const float ssum = red[0];
  if (t < 96) A[(size_t)bh * 9216 + i * 96 + t] = e / ssum;
}

// ---------------------------------------------------------------------------
// K5 v3: out = proj( from_blocks( A @ v ) ). One block = 16 attention cols.
// v loaded from column-major layout (coalesced); A@v result kept in regs so
// ao aliases vt -> 49 KB LDS -> 3 blocks/CU. grid (8,128,2), block 256.
// ---------------------------------------------------------------------------
__global__ __launch_bounds__(256, 3) void k5_av_proj(
    const float* __restrict__ vb, const float* __restrict__ A,
    const float* __restrict__ pw, float* __restrict__ out)
{
  const int t  = threadIdx.x;
  const int wg = blockIdx.x, hh = blockIdx.y, b = blockIdx.z;
  const int n0 = hh * 128 + wg * 16;
  __shared__ float smem[12288];   // phase 0-1: vt[h][r][16 nl]; phase 2-3: ao

  // phase 0: load v tile. global: 16 segments of 64B per wave; LDS scatter
  // (16u+nl banks) is 4-way on a handful of insts (negligible).
  #pragma unroll
  for (int it = 0; it < 12; ++it) {
    const int i4  = it * 256 + t;          // [0, 3072)
    const int h   = i4 / 384;
    const int q   = i4 - h * 384;
    const int r4g = q >> 6;
    const int rem = q & 63;
    const int nl  = rem >> 2;
    const int r4  = r4g * 4 + (rem & 3);
    const float4 v = *(const float4*)(vb
        + (size_t)((b * 8 + h) * 16384 + n0 + nl) * 96 + r4 * 4);
    float* dl = smem + (h * 96 + r4 * 4) * 16 + nl;
    dl[0] = v.x; dl[16] = v.y; dl[32] = v.z; dl[48] = v.w;
  }
  __syncthreads();

  // phase 1: A @ v into registers (res). A rows as float4: 4x fewer loads.
  float4 res[6][2];
  #pragma unroll 1
  for (int r = 0; r < 6; ++r) {
    const int task = r * 256 + t;           // h(8) x ip(48) x n4(4)
    const int n4 = task & 3;
    const int ip = (task >> 2) % 48;
    const int h  = task / 192;
    const int i0 = ip * 2;
    const float* arow0 = A + (size_t)((b * 8 + h) * 96 + i0) * 96;
    const float* arow1 = arow0 + 96;
    const float* vp = smem + h * 1536 + n4 * 4;
    float4 a0 = {0, 0, 0, 0}, a1 = {0, 0, 0, 0};
    #pragma unroll 2
    for (int j4 = 0; j4 < 24; ++j4) {
      const float4 w0 = *(const float4*)(arow0 + j4 * 4);
      const float4 w1 = *(const float4*)(arow1 + j4 * 4);
      const float4 v0 = *(const float4*)(vp + (j4 * 4 + 0) * 16);
      const float4 v1 = *(const float4*)(vp + (j4 * 4 + 1) * 16);
      const float4 v2 = *(const float4*)(vp + (j4 * 4 + 2) * 16);
      const float4 v3 = *(const float4*)(vp + (j4 * 4 + 3) * 16);
      a0.x += w0.x * v0.x + w0.y * v1.x + w0.z * v2.x + w0.w * v3.x;
      a0.y += w0.x * v0.y + w0.y * v1.y + w0.z * v2.y + w0.w * v3.y;
      a0.z += w0.x * v0.z + w0.y * v1.z + w0.z * v2.z + w0.w * v3.z;
      a0.w += w0.x * v0.w + w0.y * v1.w + w0.z * v2.w + w0.w * v3.w;
      a1.x += w1.x * v0.x + w1.y * v1.x + w1.z * v2.x + w1.w * v3.x;
      a1.y += w1.x * v0.y + w1.y * v1.y + w1.z * v2.y + w1.w * v3.y;
      a1.z += w1.x * v0.z + w1.y * v1.z + w1.z * v2.z + w1.w * v3.z;
      a1.w += w1.x * v0.w + w1.y * v1.w + w1.z * v2.w + w1.w * v3.w;
    }
    res[r][0] = a0; res[r][1] = a1;
  }
  __syncthreads();   // all vt reads done; smem becomes ao

  // phase 2: write res into ao[ic][p][ww]
  #pragma unroll
  for (int r = 0; r < 6; ++r) {
    const int task = r * 256 + t;
    const int n4 = task & 3;
    const int ip = (task >> 2) % 48;
    const int h  = task / 192;
    const int i0 = ip * 2, i1 = i0 + 1;
    *(float4*)(smem + ((h * 6 + (i0 >> 4)) * 16 + (i0 & 15)) * 16 + n4 * 4) = res[r][0];
    *(float4*)(smem + ((h * 6 + (i1 >> 4)) * 16 + (i1 & 15)) * 16 + n4 * 4) = res[r][1];
  }
  __syncthreads();

  // phase 3: proj 1x1: thread owns one output pixel across 48 channels
  const int xl = t & 63, ph = t >> 6;
  const int p  = ph * 4 + (xl & 3);
  const int wwl = xl >> 2;
  float sv[48];
  #pragma unroll
  for (int ic = 0; ic < 48; ++ic) sv[ic] = smem[(ic * 16 + p) * 16 + wwl];
  const int H = hh * 4 + ph;
  const int Wp = wg * 64 + xl;
  float* outp = out + ((size_t)b * 48 << SHIFT_HW) + (H << 9) + Wp;
  #pragma unroll 1
  for (int oc = 0; oc < 48; oc += 2) {
    float acc0 = 0.f, acc1 = 0.f;
    #pragma unroll
    for (int ic = 0; ic < 48; ++ic) {
      acc0 += pw[oc * 48 + ic]       * sv[ic];   // uniform -> s_loads
      acc1 += pw[(oc + 1) * 48 + ic] * sv[ic];
    }
    outp[(size_t)oc << SHIFT_HW]       = acc0;
    outp[(size_t)(oc + 1) << SHIFT_HW] = acc1;
  }
}

// ---------------------------------------------------------------------------
extern "C" void kernel_launch(void* const* d_in, const int* in_sizes, int n_in,
                              void* d_out, int out_size, void* d_ws, size_t ws_size,
                              hipStream_t stream) {
  const float* x      = (const float*)d_in[0];
  const float* qkv_w  = (const float*)d_in[1];
  const float* dw_w   = (const float*)d_in[2];
  const float* proj_w = (const float*)d_in[3];
  const float* temp   = (const float*)d_in[4];
  float* ws = (float*)d_ws;
  float* qb = ws + QB_OFF;
  float* kb = ws + KB_OFF;
  float* vb = ws + VB_OFF;
  float* G  = ws + G_OFF;
  float* sq = ws + SQ_OFF;
  float* sk = ws + SK_OFF;
  float* A  = ws + A_OFF;

  // zero G + sq + sk (contiguous region); A is fully overwritten by k4
  hipMemsetAsync(G, 0, (size_t)(147456 + 3072) * sizeof(float), stream);

  k1_qkv_dw<<<dim3(32, 32, 2), 384, 0, stream>>>(x, qkv_w, dw_w, qb, kb, vb);
  k3_gram<<<dim3(32, 16), 256, 0, stream>>>(qb, kb, G, sq, sk);
  k4_softmax<<<dim3(96, 16), 128, 0, stream>>>(G, sq, sk, temp, A);
  k5_av_proj<<<dim3(8, 128, 2), 256, 0, stream>>>(vb, A, proj_w, (float*)d_out);
}

// Round 4
// 739.683 us; speedup vs baseline: 1.3941x; 1.1208x over previous
//
#include <hip/hip_runtime.h>
#include <cstddef>

#define S 512
#define SHIFT_HW 18      // 512*512 = 1<<18
#define NCOL 16384

// workspace layout (float offsets). q/k/v are COLUMN-MAJOR blocked:
//   qb[bh][n][r], bh in [0,16), n in [0,16384), r in [0,96)
// so K1's stores (r contiguous) and K3/K5's tile loads (n-range contiguous)
// are both coalesced. Row-major gave 2x WRITE_SIZE (partial line RMW).
#define QB_OFF 0ull
#define KB_OFF 25165824ull
#define VB_OFF 50331648ull
#define G_OFF  75497472ull   // unused since v7 (partial-G lives in d_out scratch)
#define SQ_OFF 75644928ull
#define SK_OFF 75646464ull
#define A_OFF  75648000ull

#define QS_STRIDE 327    // odd (7 mod 32): depthwise reads <=2-way bank aliasing

// ---------------------------------------------------------------------------
// K1 v7: fused 1x1 qkv conv + 3x3 depthwise (zero pad) + scatter to
// column-major blocked layout. grid (32,32,2), block 384. 16x16 tile.
// v4: 1x1 weights double-buffered in LDS (broadcast b128) - VALUBusy 34->57%.
// v6: 2px x 12oc register tile with oh = t&1 -- REGRESSED: even/odd lanes
// read weight addrs 2304B apart (576 fl == 0 mod 32 banks) -> same-bank
// different-address on every weight b128: 4.0e7 conflict cycles/dispatch.
// v7: oh assigned PER WAVE (wave&1); wave-pair (2j,2j+1) covers pixel pairs
// 64j..64j+63 with oh=0/1. Weight ds_read_b128 is wave-uniform -> HW
// broadcast, zero conflicts, and weight LDS return traffic stays halved vs
// v5 (5.3 MB/block vs 10.6). qs writes are stride-2 in-wave = 2-way = free.
// ---------------------------------------------------------------------------
__global__ __launch_bounds__(384, 3) void k1_qkv_dw(
    const float* __restrict__ x, const float* __restrict__ qkv_w,
    const float* __restrict__ dw_w,
    float* __restrict__ qb, float* __restrict__ kb, float* __restrict__ vb)
{
  const int t = threadIdx.x;
  const int b = blockIdx.z;
  const int W0 = blockIdx.x * 16, H0 = blockIdx.y * 16;
  __shared__ float qs[24 * QS_STRIDE];   // 24-ch group over 18x18 halo
  __shared__ float dws[1296];            // all depthwise weights (144 ch x 9)
  __shared__ float qws[2][1152];         // double-buffered 1x1 weights (24x48)

  for (int i = t; i < 1296; i += 384) dws[i] = dw_w[i];
  // prologue: stage group 0 weights
  for (int i = t; i < 288; i += 384)
    ((float4*)qws[0])[i] = ((const float4*)qkv_w)[i];

  // pointwise task: wave-pair (2j,2j+1) owns pixel pairs 64j+ln; oh per wave.
  const int wv = t >> 6, ln = t & 63;
  const int oh = wv & 1;                 // oc half: 0 -> ocs 0-11, 1 -> 12-23
  const int P  = (wv >> 1) * 64 + ln;    // pixel-pair id
  const bool act = (P < 162);
  const int p0 = P * 2, p1 = p0 + 1;     // same halo row (row width 18 even)
  const int hy = p0 / 18, hx0 = p0 % 18;
  const int Hg  = H0 - 1 + hy;
  const int Wg0 = W0 - 1 + hx0, Wg1 = Wg0 + 1;
  const bool inb0 = act && (Hg >= 0) && (Hg < S) && (Wg0 >= 0) && (Wg0 < S);
  const bool inb1 = act && (Hg >= 0) && (Hg < S) && (Wg1 < S); // Wg1>=1
  const float* xb0 = x + ((size_t)b * 48 << SHIFT_HW) + (inb0 ? ((Hg << 9) + Wg0) : 0);
  const float* xb1 = x + ((size_t)b * 48 << SHIFT_HW) + (inb1 ? ((Hg << 9) + Wg1) : 0);
  float xv0[48], xv1[48];
  #pragma unroll
  for (int ic = 0; ic < 48; ++ic) {
    xv0[ic] = inb0 ? xb0[(size_t)ic << SHIFT_HW] : 0.0f;
    xv1[ic] = inb1 ? xb1[(size_t)ic << SHIFT_HW] : 0.0f;
  }

  // inactive lanes (wv>=4, ln>=34): 60 weight stagers
  const int sid = (wv - 4) * 30 + (ln - 34);   // valid iff !act

  // depthwise task: thread owns (ch, output row y), all 16 x-positions
  const int ch = t >> 4;                 // 0..23 (channel within group)
  const int y  = t & 15;                 // output row within tile
  const int nb = (blockIdx.y * 4 + (y >> 2)) * 128 + blockIdx.x * 4;
  const float* qrow = qs + ch * QS_STRIDE + y * 18;  // halo rows y..y+2

  __syncthreads();   // dws + qws[0] ready

  #pragma unroll 1
  for (int g = 0; g < 6; ++g) {
    // ---- pointwise GEMM: 2 pixels x 12 ocs per thread, wave-uniform weights
    if (act) {
      const float* wgp = qws[g & 1] + oh * 576;
      #pragma unroll
      for (int oc = 0; oc < 12; ++oc) {
        float a0 = 0.f, a1 = 0.f;
        const float* wr = wgp + oc * 48;
        #pragma unroll
        for (int ic4 = 0; ic4 < 12; ++ic4) {
          const float4 w = *(const float4*)(wr + ic4 * 4);
          a0 += w.x * xv0[ic4 * 4 + 0] + w.y * xv0[ic4 * 4 + 1]
              + w.z * xv0[ic4 * 4 + 2] + w.w * xv0[ic4 * 4 + 3];
          a1 += w.x * xv1[ic4 * 4 + 0] + w.y * xv1[ic4 * 4 + 1]
              + w.z * xv1[ic4 * 4 + 2] + w.w * xv1[ic4 * 4 + 3];
        }
        const int ocg = oh * 12 + oc;
        qs[ocg * QS_STRIDE + p0] = a0;
        qs[ocg * QS_STRIDE + p1] = a1;
      }
    } else if (g < 5) {
      // idle lanes stage next group's weights into the other buffer.
      // qws[(g+1)&1] was last READ in pointwise(g-1); two barriers separate.
      float4* dstq = (float4*)qws[(g + 1) & 1];
      const float4* srcq = (const float4*)qkv_w + (g + 1) * 288;
      for (int i = sid; i < 288; i += 60) dstq[i] = srcq[i];
    }
    __syncthreads();

    // ---- depthwise 3x3 (sliding window) + coalesced float4 stores ----
    // out[xq] -> n = nb + (xq>>2), r = c*16 + (y&3)*4 + (xq&3):
    // one float4 per n, r contiguous. A wave's 16B pieces tile 128-256B
    // contiguous segments -> fully dirtied lines, no RMW.
    const int tensor = g >> 1;            // 0=q,1=k,2=v
    const int chbase = (g & 1) * 24;
    const int chg  = chbase + ch;         // channel within tensor
    const int head = chg / 6, c = chg - 6 * head;
    float* dst = (tensor == 0) ? qb : (tensor == 1) ? kb : vb;
    float* dstp = dst + (size_t)((b * 8 + head) * 16384 + nb) * 96
                      + c * 16 + (y & 3) * 4;
    const float* wp = dws + (tensor * 48 + chg) * 9;
    const float w0 = wp[0], w1 = wp[1], w2 = wp[2];
    const float w3 = wp[3], w4 = wp[4], w5 = wp[5];
    const float w6 = wp[6], w7 = wp[7], w8 = wp[8];

    float p00 = qrow[0], p01 = qrow[18], p02 = qrow[36];
    float p10 = qrow[1], p11 = qrow[19], p12 = qrow[37];
    #pragma unroll
    for (int wl = 0; wl < 4; ++wl) {
      float o[4];
      #pragma unroll
      for (int u = 0; u < 4; ++u) {
        const int xq = wl * 4 + u;
        const float n0 = qrow[xq + 2];
        const float n1 = qrow[xq + 20];
        const float n2 = qrow[xq + 38];
        o[u] = w0 * p00 + w1 * p10 + w2 * n0
             + w3 * p01 + w4 * p11 + w5 * n1
             + w6 * p02 + w7 * p12 + w8 * n2;
        p00 = p10; p01 = p11; p02 = p12;
        p10 = n0;  p11 = n1;  p12 = n2;
      }
      float4 v4 = {o[0], o[1], o[2], o[3]};
      *(float4*)(dstp + (size_t)wl * 96) = v4;
    }
    __syncthreads();
  }
}

// ---------------------------------------------------------------------------
// K3 v5: Gram G[bh] = q@k^T (96x96, K=16384) + row sum-squares. Column-major
// input: tile load is a flat contiguous copy. grid (32,16), 512-col chunks.
// v5: NO G atomics. Each block stores its 9216-float partial to Gp (scratch
// in d_out, dead until K5 overwrites it); K4 sums the 32 partials. Round-2
// A/B: halving atomics to the 147KB G region bought ~98us -- contention on
// device-scope f32 atomics was the cost. sq/sk keep atomics (98K ops, minor).
// ---------------------------------------------------------------------------
__global__ __launch_bounds__(256, 3) void k3_gram(
    const float* __restrict__ qb, const float* __restrict__ kb,
    float* __restrict__ Gp, float* __restrict__ sq, float* __restrict__ sk)
{
  const int t  = threadIdx.x;
  const int bh = blockIdx.y;
  const int n0 = blockIdx.x * 512;
  __shared__ float qt[6144];   // [64 n][96 r] flat
  __shared__ float kt[6144];
  const int ti = t >> 4, tj = t & 15;
  float acc[6][6];
  #pragma unroll
  for (int r = 0; r < 6; ++r)
    #pragma unroll
    for (int s_ = 0; s_ < 6; ++s_) acc[r][s_] = 0.f;
  float ss = 0.f;
  const float* qbase = qb + (size_t)bh * 16384 * 96;
  const float* kbase = kb + (size_t)bh * 16384 * 96;

  #pragma unroll 1
  for (int st = 0; st < 8; ++st) {
    __syncthreads();
    const float4* qsrc = (const float4*)(qbase + (size_t)(n0 + st * 64) * 96);
    const float4* ksrc = (const float4*)(kbase + (size_t)(n0 + st * 64) * 96);
    #pragma unroll
    for (int r = 0; r < 6; ++r) {
      const int f4 = r * 256 + t;
      ((float4*)qt)[f4] = qsrc[f4];
      ((float4*)kt)[f4] = ksrc[f4];
    }
    __syncthreads();
    #pragma unroll 2
    for (int nn = 0; nn < 64; ++nn) {
      const float* qr = qt + nn * 96 + ti * 6;
      const float* kr = kt + nn * 96 + tj * 6;
      const float2 q0 = *(const float2*)(qr);
      const float2 q1 = *(const float2*)(qr + 2);
      const float2 q2 = *(const float2*)(qr + 4);
      const float2 k0 = *(const float2*)(kr);
      const float2 k1 = *(const float2*)(kr + 2);
      const float2 k2 = *(const float2*)(kr + 4);
      const float qv[6] = {q0.x, q0.y, q1.x, q1.y, q2.x, q2.y};
      const float kv[6] = {k0.x, k0.y, k1.x, k1.y, k2.x, k2.y};
      #pragma unroll
      for (int r = 0; r < 6; ++r)
        #pragma unroll
        for (int s_ = 0; s_ < 6; ++s_)
          acc[r][s_] += qv[r] * kv[s_];
    }
    if (t < 192) {                          // sum-squares for norms
      const float* base = (t < 96) ? qt : kt;
      const int srow = (t < 96) ? t : (t - 96);
      float s2 = 0.f;
      #pragma unroll 8
      for (int nn = 0; nn < 64; ++nn) {
        const float v = base[nn * 96 + srow];
        s2 += v * v;
      }
      ss += s2;
    }
  }
  // non-atomic partial store: Gp[p][bh][9216], p = blockIdx.x
  float* Gb = Gp + (size_t)(blockIdx.x * 16 + bh) * 9216;
  #pragma unroll
  for (int r = 0; r < 6; ++r)
    #pragma unroll
    for (int s_ = 0; s_ < 6; ++s_)
      Gb[(ti * 6 + r) * 96 + (tj * 6 + s_)] = acc[r][s_];
  if (t < 96)       atomicAdd(sq + bh * 96 + t,        ss);
  else if (t < 192) atomicAdd(sk + bh * 96 + (t - 96), ss);
}

// ---------------------------------------------------------------------------
// K4 v2: sum 32 Gram partials + normalize logits + temperature + row softmax.
// grid (96 rows, 16 bh), block 128. Partial sum: 32 coalesced 384B loads
// per block (18.9 MB total, L2/L3-resident).
// ---------------------------------------------------------------------------
__global__ __launch_bounds__(128) void k4_softmax(
    const float* __restrict__ Gp, const float* __restrict__ sq,
    const float* __restrict__ sk, const float* __restrict__ temp,
    float* __restrict__ A)
{
  const int i  = blockIdx.x;
  const int bh = blockIdx.y;
  const int h  = bh & 7;
  const int t  = threadIdx.x;
  __shared__ float red[128];

  const float nq    = fmaxf(sqrtf(sq[bh * 96 + i]), 1e-12f);
  const float scale = temp[h] / nq;
  float logit = 0.f, val = -1e30f;
  if (t < 96) {
    float gsum = 0.f;
    #pragma unroll 8
    for (int p = 0; p < 32; ++p)
      gsum += Gp[(size_t)(p * 16 + bh) * 9216 + i * 96 + t];
    const float nk = fmaxf(sqrtf(sk[bh * 96 + t]), 1e-12f);
    logit = gsum * scale / nk;
    val = logit;
  }
  red[t] = val; __syncthreads();
  #pragma unroll
  for (int o = 64; o > 0; o >>= 1) {
    if (t < o) red[t] = fmaxf(red[t], red[t + o]);
    __syncthreads();
  }
  const float m = red[0]; __syncthreads();
  const float e = (t < 96) ? __expf(logit - m) : 0.f;
  red[t] = e; __syncthreads();
  #pragma unroll
  for (int o = 64; o > 0; o >>= 1) {
    if (t < o) red[t] += red[t + o];
    __syncthreads();
  }
  const float ssum = red[0];
  if (t < 96) A[(size_t)bh * 9216 + i * 96 + t] = e / ssum;
}

// ---------------------------------------------------------------------------
// K5 v3: out = proj( from_blocks( A @ v ) ). One block = 16 attention cols.
// v loaded from column-major layout (coalesced); A@v result kept in regs so
// ao aliases vt -> 49 KB LDS -> 3 blocks/CU. grid (8,128,2), block 256.
// NOTE: K5 fully overwrites d_out (every b, oc, H, W) -- which is why d_out
// doubles as K3/K4's partial-G scratch earlier in the stream.
// ---------------------------------------------------------------------------
__global__ __launch_bounds__(256, 3) void k5_av_proj(
    const float* __restrict__ vb, const float* __restrict__ A,
    const float* __restrict__ pw, float* __restrict__ out)
{
  const int t  = threadIdx.x;
  const int wg = blockIdx.x, hh = blockIdx.y, b = blockIdx.z;
  const int n0 = hh * 128 + wg * 16;
  __shared__ float smem[12288];   // phase 0-1: vt[h][r][16 nl]; phase 2-3: ao

  // phase 0: load v tile. global: 16 segments of 64B per wave; LDS scatter
  // (16u+nl banks) is 4-way on a handful of insts (negligible).
  #pragma unroll
  for (int it = 0; it < 12; ++it) {
    const int i4  = it * 256 + t;          // [0, 3072)
    const int h   = i4 / 384;
    const int q   = i4 - h * 384;
    const int r4g = q >> 6;
    const int rem = q & 63;
    const int nl  = rem >> 2;
    const int r4  = r4g * 4 + (rem & 3);
    const float4 v = *(const float4*)(vb
        + (size_t)((b * 8 + h) * 16384 + n0 + nl) * 96 + r4 * 4);
    float* dl = smem + (h * 96 + r4 * 4) * 16 + nl;
    dl[0] = v.x; dl[16] = v.y; dl[32] = v.z; dl[48] = v.w;
  }
  __syncthreads();

  // phase 1: A @ v into registers (res). A rows as float4: 4x fewer loads.
  float4 res[6][2];
  #pragma unroll 1
  for (int r = 0; r < 6; ++r) {
    const int task = r * 256 + t;           // h(8) x ip(48) x n4(4)
    const int n4 = task & 3;
    const int ip = (task >> 2) % 48;
    const int h  = task / 192;
    const int i0 = ip * 2;
    const float* arow0 = A + (size_t)((b * 8 + h) * 96 + i0) * 96;
    const float* arow1 = arow0 + 96;
    const float* vp = smem + h * 1536 + n4 * 4;
    float4 a0 = {0, 0, 0, 0}, a1 = {0, 0, 0, 0};
    #pragma unroll 2
    for (int j4 = 0; j4 < 24; ++j4) {
      const float4 w0 = *(const float4*)(arow0 + j4 * 4);
      const float4 w1 = *(const float4*)(arow1 + j4 * 4);
      const float4 v0 = *(const float4*)(vp + (j4 * 4 + 0) * 16);
      const float4 v1 = *(const float4*)(vp + (j4 * 4 + 1) * 16);
      const float4 v2 = *(const float4*)(vp + (j4 * 4 + 2) * 16);
      const float4 v3 = *(const float4*)(vp + (j4 * 4 + 3) * 16);
      a0.x += w0.x * v0.x + w0.y * v1.x + w0.z * v2.x + w0.w * v3.x;
      a0.y += w0.x * v0.y + w0.y * v1.y + w0.z * v2.y + w0.w * v3.y;
      a0.z += w0.x * v0.z + w0.y * v1.z + w0.z * v2.z + w0.w * v3.z;
      a0.w += w0.x * v0.w + w0.y * v1.w + w0.z * v2.w + w0.w * v3.w;
      a1.x += w1.x * v0.x + w1.y * v1.x + w1.z * v2.x + w1.w * v3.x;
      a1.y += w1.x * v0.y + w1.y * v1.y + w1.z * v2.y + w1.w * v3.y;
      a1.z += w1.x * v0.z + w1.y * v1.z + w1.z * v2.z + w1.w * v3.z;
      a1.w += w1.x * v0.w + w1.y * v1.w + w1.z * v2.w + w1.w * v3.w;
    }
    res[r][0] = a0; res[r][1] = a1;
  }
  __syncthreads();   // all vt reads done; smem becomes ao

  // phase 2: write res into ao[ic][p][ww]
  #pragma unroll
  for (int r = 0; r < 6; ++r) {
    const int task = r * 256 + t;
    const int n4 = task & 3;
    const int ip = (task >> 2) % 48;
    const int h  = task / 192;
    const int i0 = ip * 2, i1 = i0 + 1;
    *(float4*)(smem + ((h * 6 + (i0 >> 4)) * 16 + (i0 & 15)) * 16 + n4 * 4) = res[r][0];
    *(float4*)(smem + ((h * 6 + (i1 >> 4)) * 16 + (i1 & 15)) * 16 + n4 * 4) = res[r][1];
  }
  __syncthreads();

  // phase 3: proj 1x1: thread owns one output pixel across 48 channels
  const int xl = t & 63, ph = t >> 6;
  const int p  = ph * 4 + (xl & 3);
  const int wwl = xl >> 2;
  float sv[48];
  #pragma unroll
  for (int ic = 0; ic < 48; ++ic) sv[ic] = smem[(ic * 16 + p) * 16 + wwl];
  const int H = hh * 4 + ph;
  const int Wp = wg * 64 + xl;
  float* outp = out + ((size_t)b * 48 << SHIFT_HW) + (H << 9) + Wp;
  #pragma unroll 1
  for (int oc = 0; oc < 48; oc += 2) {
    float acc0 = 0.f, acc1 = 0.f;
    #pragma unroll
    for (int ic = 0; ic < 48; ++ic) {
      acc0 += pw[oc * 48 + ic]       * sv[ic];   // uniform -> s_loads
      acc1 += pw[(oc + 1) * 48 + ic] * sv[ic];
    }
    outp[(size_t)oc << SHIFT_HW]       = acc0;
    outp[(size_t)(oc + 1) << SHIFT_HW] = acc1;
  }
}

// ---------------------------------------------------------------------------
extern "C" void kernel_launch(void* const* d_in, const int* in_sizes, int n_in,
                              void* d_out, int out_size, void* d_ws, size_t ws_size,
                              hipStream_t stream) {
  const float* x      = (const float*)d_in[0];
  const float* qkv_w  = (const float*)d_in[1];
  const float* dw_w   = (const float*)d_in[2];
  const float* proj_w = (const float*)d_in[3];
  const float* temp   = (const float*)d_in[4];
  float* ws = (float*)d_ws;
  float* qb = ws + QB_OFF;
  float* kb = ws + KB_OFF;
  float* vb = ws + VB_OFF;
  float* sq = ws + SQ_OFF;
  float* sk = ws + SK_OFF;
  float* A  = ws + A_OFF;
  // partial-G scratch lives in d_out (18.9 MB needed, 50.3 MB available);
  // K5 fully overwrites d_out afterwards.
  float* Gp = (float*)d_out;

  // zero sq + sk only (G atomics are gone)
  hipMemsetAsync(sq, 0, (size_t)3072 * sizeof(float), stream);

  k1_qkv_dw<<<dim3(32, 32, 2), 384, 0, stream>>>(x, qkv_w, dw_w, qb, kb, vb);
  k3_gram<<<dim3(32, 16), 256, 0, stream>>>(qb, kb, Gp, sq, sk);
  k4_softmax<<<dim3(96, 16), 128, 0, stream>>>(Gp, sq, sk, temp, A);
  k5_av_proj<<<dim3(8, 128, 2), 256, 0, stream>>>(vb, A, proj_w, (float*)d_out);
}

// Round 5
// 719.672 us; speedup vs baseline: 1.4329x; 1.0278x over previous
//
#include <hip/hip_runtime.h>
#include <cstddef>

#define S 512
#define SHIFT_HW 18      // 512*512 = 1<<18
#define NCOL 16384

// workspace layout (float offsets). q/k/v are COLUMN-MAJOR blocked:
//   qb[bh][n][r], bh in [0,16), n in [0,16384), r in [0,96)
// so K1's stores (r contiguous) and K3/K5's tile loads (n-range contiguous)
// are both coalesced. Row-major gave 2x WRITE_SIZE (partial line RMW).
#define QB_OFF 0ull
#define KB_OFF 25165824ull
#define VB_OFF 50331648ull
#define SQ_OFF 75644928ull
#define SK_OFF 75646464ull
#define A_OFF  75648000ull

#define QS_STRIDE 324    // 18x18 halo exactly; (4*dch+18*dy) mod 32 <=2-way

// ---------------------------------------------------------------------------
// K1 v8: fused 1x1 qkv conv + 3x3 depthwise (zero pad) + scatter to
// column-major blocked layout. grid (32,32,2), block 384. 16x16 tile.
// History: v4 LDS weights (VALUBusy 34->57); v6/v7 register tiling REGRESSED
// (VGPR 56->84 dropped a resident block; uniform ds_read broadcast is HW-
// deduped so the traffic win was moot). v8 reverts to v5 dataflow (1px x
// 24oc, VGPR ~56) and attacks the real limiter -- occupancy for latency
// hiding across 12 full-drain barriers/block: LDS diet 46080->40896 B
// (QS_STRIDE 324, single qws staged DURING the depthwise phase where qws is
// idle; barriers order pw-reads -> overwrite) => 4 blocks/CU, 24 waves.
// ---------------------------------------------------------------------------
__global__ __launch_bounds__(384, 6) void k1_qkv_dw(
    const float* __restrict__ x, const float* __restrict__ qkv_w,
    const float* __restrict__ dw_w,
    float* __restrict__ qb, float* __restrict__ kb, float* __restrict__ vb)
{
  const int t = threadIdx.x;
  const int b = blockIdx.z;
  const int W0 = blockIdx.x * 16, H0 = blockIdx.y * 16;
  __shared__ float qs[24 * QS_STRIDE];   // 24-ch group over 18x18 halo
  __shared__ float dws[1296];            // all depthwise weights (144 ch x 9)
  __shared__ float qws[1152];            // single-buffered 1x1 weights (24x48)

  for (int i = t; i < 1296; i += 384) dws[i] = dw_w[i];
  // prologue: stage group 0 weights
  for (int i = t; i < 288; i += 384)
    ((float4*)qws)[i] = ((const float4*)qkv_w)[i];

  // per-thread halo pixel, x channels held in registers across all 6 groups
  float xv[48];
  const int p  = t;
  const int hy = p / 18, hx = p % 18;            // valid for t<324
  const int Hg = H0 - 1 + hy, Wg = W0 - 1 + hx;
  const bool inb = (t < 324) && (Hg >= 0) && (Hg < S) && (Wg >= 0) && (Wg < S);
  const float* xb = x + ((size_t)b * 48 << SHIFT_HW) + (inb ? ((Hg << 9) + Wg) : 0);
  #pragma unroll
  for (int ic = 0; ic < 48; ++ic) {
    float v = 0.0f;
    if (inb) v = xb[(size_t)ic << SHIFT_HW];
    xv[ic] = v;
  }

  // depthwise task: thread owns (ch, output row y), all 16 x-positions
  const int ch = t >> 4;                 // 0..23 (channel within group)
  const int y  = t & 15;                 // output row within tile
  const int nb = (blockIdx.y * 4 + (y >> 2)) * 128 + blockIdx.x * 4;
  const float* qrow = qs + ch * QS_STRIDE + y * 18;  // halo rows y..y+2

  __syncthreads();   // dws + qws(g=0) ready

  #pragma unroll 1
  for (int g = 0; g < 6; ++g) {
    // ---- pointwise GEMM: 24 output channels for this group, halo pixels ----
    // weights from LDS, wave-uniform b128 reads (HW broadcast, conflict-free)
    if (t < 324) {
      const float* wgp = qws;
      #pragma unroll
      for (int oc = 0; oc < 24; oc += 2) {
        float a0 = 0.f, a1 = 0.f;
        #pragma unroll
        for (int ic4 = 0; ic4 < 12; ++ic4) {
          const float4 w0 = *(const float4*)(wgp + oc * 48 + ic4 * 4);
          const float4 w1 = *(const float4*)(wgp + (oc + 1) * 48 + ic4 * 4);
          a0 += w0.x * xv[ic4 * 4 + 0] + w0.y * xv[ic4 * 4 + 1]
              + w0.z * xv[ic4 * 4 + 2] + w0.w * xv[ic4 * 4 + 3];
          a1 += w1.x * xv[ic4 * 4 + 0] + w1.y * xv[ic4 * 4 + 1]
              + w1.z * xv[ic4 * 4 + 2] + w1.w * xv[ic4 * 4 + 3];
        }
        qs[oc * QS_STRIDE + p]       = a0;
        qs[(oc + 1) * QS_STRIDE + p] = a1;
      }
    }
    __syncthreads();

    // ---- stage next group's weights (qws idle during depthwise) ----------
    // load issued at phase start, ds_write at phase end: HBM latency hides
    // under the depthwise compute. Barriers order pw(g) reads -> overwrite.
    float4 stg;
    const bool do_stage = (g < 5) && (t < 288);
    if (do_stage) stg = *((const float4*)qkv_w + (g + 1) * 288 + t);

    // ---- depthwise 3x3 (sliding window) + coalesced float4 stores ----
    // out[xq] -> n = nb + (xq>>2), r = c*16 + (y&3)*4 + (xq&3):
    // one float4 per n, r contiguous. A wave's 16B pieces tile 128-256B
    // contiguous segments -> fully dirtied lines, no RMW.
    const int tensor = g >> 1;            // 0=q,1=k,2=v
    const int chbase = (g & 1) * 24;
    const int chg  = chbase + ch;         // channel within tensor
    const int head = chg / 6, c = chg - 6 * head;
    float* dst = (tensor == 0) ? qb : (tensor == 1) ? kb : vb;
    float* dstp = dst + (size_t)((b * 8 + head) * 16384 + nb) * 96
                      + c * 16 + (y & 3) * 4;
    const float* wp = dws + (tensor * 48 + chg) * 9;
    const float w0 = wp[0], w1 = wp[1], w2 = wp[2];
    const float w3 = wp[3], w4 = wp[4], w5 = wp[5];
    const float w6 = wp[6], w7 = wp[7], w8 = wp[8];

    float p00 = qrow[0], p01 = qrow[18], p02 = qrow[36];
    float p10 = qrow[1], p11 = qrow[19], p12 = qrow[37];
    #pragma unroll
    for (int wl = 0; wl < 4; ++wl) {
      float o[4];
      #pragma unroll
      for (int u = 0; u < 4; ++u) {
        const int xq = wl * 4 + u;
        const float n0 = qrow[xq + 2];
        const float n1 = qrow[xq + 20];
        const float n2 = qrow[xq + 38];
        o[u] = w0 * p00 + w1 * p10 + w2 * n0
             + w3 * p01 + w4 * p11 + w5 * n1
             + w6 * p02 + w7 * p12 + w8 * n2;
        p00 = p10; p01 = p11; p02 = p12;
        p10 = n0;  p11 = n1;  p12 = n2;
      }
      float4 v4 = {o[0], o[1], o[2], o[3]};
      *(float4*)(dstp + (size_t)wl * 96) = v4;
    }

    if (do_stage) ((float4*)qws)[t] = stg;
    __syncthreads();
  }
}

// ---------------------------------------------------------------------------
// K3 v5: Gram G[bh] = q@k^T (96x96, K=16384) + row sum-squares. Column-major
// input: tile load is a flat contiguous copy. grid (32,16), 512-col chunks.
// No G atomics: per-block partial stored to Gp (d_out scratch); K4 reduces.
// ---------------------------------------------------------------------------
__global__ __launch_bounds__(256, 3) void k3_gram(
    const float* __restrict__ qb, const float* __restrict__ kb,
    float* __restrict__ Gp, float* __restrict__ sq, float* __restrict__ sk)
{
  const int t  = threadIdx.x;
  const int bh = blockIdx.y;
  const int n0 = blockIdx.x * 512;
  __shared__ float qt[6144];   // [64 n][96 r] flat
  __shared__ float kt[6144];
  const int ti = t >> 4, tj = t & 15;
  float acc[6][6];
  #pragma unroll
  for (int r = 0; r < 6; ++r)
    #pragma unroll
    for (int s_ = 0; s_ < 6; ++s_) acc[r][s_] = 0.f;
  float ss = 0.f;
  const float* qbase = qb + (size_t)bh * 16384 * 96;
  const float* kbase = kb + (size_t)bh * 16384 * 96;

  #pragma unroll 1
  for (int st = 0; st < 8; ++st) {
    __syncthreads();
    const float4* qsrc = (const float4*)(qbase + (size_t)(n0 + st * 64) * 96);
    const float4* ksrc = (const float4*)(kbase + (size_t)(n0 + st * 64) * 96);
    #pragma unroll
    for (int r = 0; r < 6; ++r) {
      const int f4 = r * 256 + t;
      ((float4*)qt)[f4] = qsrc[f4];
      ((float4*)kt)[f4] = ksrc[f4];
    }
    __syncthreads();
    #pragma unroll 2
    for (int nn = 0; nn < 64; ++nn) {
      const float* qr = qt + nn * 96 + ti * 6;
      const float* kr = kt + nn * 96 + tj * 6;
      const float2 q0 = *(const float2*)(qr);
      const float2 q1 = *(const float2*)(qr + 2);
      const float2 q2 = *(const float2*)(qr + 4);
      const float2 k0 = *(const float2*)(kr);
      const float2 k1 = *(const float2*)(kr + 2);
      const float2 k2 = *(const float2*)(kr + 4);
      const float qv[6] = {q0.x, q0.y, q1.x, q1.y, q2.x, q2.y};
      const float kv[6] = {k0.x, k0.y, k1.x, k1.y, k2.x, k2.y};
      #pragma unroll
      for (int r = 0; r < 6; ++r)
        #pragma unroll
        for (int s_ = 0; s_ < 6; ++s_)
          acc[r][s_] += qv[r] * kv[s_];
    }
    if (t < 192) {                          // sum-squares for norms
      const float* base = (t < 96) ? qt : kt;
      const int srow = (t < 96) ? t : (t - 96);
      float s2 = 0.f;
      #pragma unroll 8
      for (int nn = 0; nn < 64; ++nn) {
        const float v = base[nn * 96 + srow];
        s2 += v * v;
      }
      ss += s2;
    }
  }
  // non-atomic partial store: Gp[p][bh][9216], p = blockIdx.x
  float* Gb = Gp + (size_t)(blockIdx.x * 16 + bh) * 9216;
  #pragma unroll
  for (int r = 0; r < 6; ++r)
    #pragma unroll
    for (int s_ = 0; s_ < 6; ++s_)
      Gb[(ti * 6 + r) * 96 + (tj * 6 + s_)] = acc[r][s_];
  if (t < 96)       atomicAdd(sq + bh * 96 + t,        ss);
  else if (t < 192) atomicAdd(sk + bh * 96 + (t - 96), ss);
}

// ---------------------------------------------------------------------------
// K4 v2: sum 32 Gram partials + normalize logits + temperature + row softmax.
// grid (96 rows, 16 bh), block 128.
// ---------------------------------------------------------------------------
__global__ __launch_bounds__(128) void k4_softmax(
    const float* __restrict__ Gp, const float* __restrict__ sq,
    const float* __restrict__ sk, const float* __restrict__ temp,
    float* __restrict__ A)
{
  const int i  = blockIdx.x;
  const int bh = blockIdx.y;
  const int h  = bh & 7;
  const int t  = threadIdx.x;
  __shared__ float red[128];

  const float nq    = fmaxf(sqrtf(sq[bh * 96 + i]), 1e-12f);
  const float scale = temp[h] / nq;
  float logit = 0.f, val = -1e30f;
  if (t < 96) {
    float gsum = 0.f;
    #pragma unroll 8
    for (int p = 0; p < 32; ++p)
      gsum += Gp[(size_t)(p * 16 + bh) * 9216 + i * 96 + t];
    const float nk = fmaxf(sqrtf(sk[bh * 96 + t]), 1e-12f);
    logit = gsum * scale / nk;
    val = logit;
  }
  red[t] = val; __syncthreads();
  #pragma unroll
  for (int o = 64; o > 0; o >>= 1) {
    if (t < o) red[t] = fmaxf(red[t], red[t + o]);
    __syncthreads();
  }
  const float m = red[0]; __syncthreads();
  const float e = (t < 96) ? __expf(logit - m) : 0.f;
  red[t] = e; __syncthreads();
  #pragma unroll
  for (int o = 64; o > 0; o >>= 1) {
    if (t < o) red[t] += red[t + o];
    __syncthreads();
  }
  const float ssum = red[0];
  if (t < 96) A[(size_t)bh * 9216 + i * 96 + t] = e / ssum;
}

// ---------------------------------------------------------------------------
// K5 v4: out = proj( from_blocks( A @ v ) ). One block = 16 attention cols.
// v4 changes vs v3 (which re-read ~2.4 GB of A through L2/L3 -- each block
// touched full A-for-b, each thread 1152 A-floats):
//  (a) block 256->384 threads: task space factors EXACTLY as
//      thread=(h(8) x ip(48)), n4=0..3 inner -> each thread reads its 2
//      A-rows ONCE (192 floats): A traffic 2.42 GB -> 0.60 GB, and vt LDS
//      reads become wave-broadcast (lanes share h).
//  (b) XCD swizzle: flat 2048-block grid, batch = XCD/4 -> per-XCD A set
//      2.36 MB < 4 MB L2 (batches no longer thrash each other's L2).
//  (c) phase-2/3 ww-quad rotated by (p>>1) to spread write banks.
// Per-output fp sum order (j4 outer, u inner) identical to v3.
// ---------------------------------------------------------------------------
__global__ __launch_bounds__(384, 4) void k5_av_proj(
    const float* __restrict__ vb, const float* __restrict__ A,
    const float* __restrict__ pw, float* __restrict__ out)
{
  const int t  = threadIdx.x;
  // XCD-aware decode: consecutive blockIdx round-robin XCDs (mod 8).
  // XCDs 0-3 -> b=0, XCDs 4-7 -> b=1; within-b index covers 1024 tiles.
  const int flat = blockIdx.x;
  const int xcd  = flat & 7;
  const int b    = xcd >> 2;
  const int idx  = (xcd & 3) * 256 + (flat >> 3);   // [0,1024)
  const int wg   = idx & 7, hh = idx >> 3;
  const int n0 = hh * 128 + wg * 16;
  __shared__ float smem[12288];   // phase 0-1: vt[h][r][16 nl]; phase 2-3: ao

  // phase 0: load v tile. global: 16 segments of 64B per wave; LDS scatter
  // (16u+nl banks) is 4-way on a handful of insts (negligible).
  #pragma unroll
  for (int it = 0; it < 8; ++it) {
    const int i4  = it * 384 + t;          // [0, 3072)
    const int h   = i4 / 384;
    const int q   = i4 - h * 384;
    const int r4g = q >> 6;
    const int rem = q & 63;
    const int nl  = rem >> 2;
    const int r4  = r4g * 4 + (rem & 3);
    const float4 v = *(const float4*)(vb
        + (size_t)((b * 8 + h) * 16384 + n0 + nl) * 96 + r4 * 4);
    float* dl = smem + (h * 96 + r4 * 4) * 16 + nl;
    dl[0] = v.x; dl[16] = v.y; dl[32] = v.z; dl[48] = v.w;
  }
  __syncthreads();

  // phase 1: A @ v. thread owns (h, ip): output rows i0=2ip, i0+1, all 4 n4.
  const int h  = t / 48;
  const int ip = t - h * 48;
  const int i0 = ip * 2;
  const float* arow0 = A + (size_t)((b * 8 + h) * 96 + i0) * 96;
  const float* arow1 = arow0 + 96;
  const float* vbase = smem + h * 1536;
  float4 r0[4], r1[4];
  #pragma unroll
  for (int n4 = 0; n4 < 4; ++n4) {
    r0[n4] = float4{0, 0, 0, 0};
    r1[n4] = float4{0, 0, 0, 0};
  }
  #pragma unroll 2
  for (int j4 = 0; j4 < 24; ++j4) {
    const float4 w0 = *(const float4*)(arow0 + j4 * 4);
    const float4 w1 = *(const float4*)(arow1 + j4 * 4);
    const float w0a[4] = {w0.x, w0.y, w0.z, w0.w};
    const float w1a[4] = {w1.x, w1.y, w1.z, w1.w};
    #pragma unroll
    for (int u = 0; u < 4; ++u) {
      const float* vp = vbase + (j4 * 4 + u) * 16;
      const float wu0 = w0a[u], wu1 = w1a[u];
      #pragma unroll
      for (int n4 = 0; n4 < 4; ++n4) {
        const float4 vv = *(const float4*)(vp + n4 * 4);
        r0[n4].x += wu0 * vv.x; r0[n4].y += wu0 * vv.y;
        r0[n4].z += wu0 * vv.z; r0[n4].w += wu0 * vv.w;
        r1[n4].x += wu1 * vv.x; r1[n4].y += wu1 * vv.y;
        r1[n4].z += wu1 * vv.z; r1[n4].w += wu1 * vv.w;
      }
    }
  }
  __syncthreads();   // all vt reads done; smem becomes ao

  // phase 2: write res into ao. logical layout ao[ic][p][ww] with the ww-quad
  // rotated by (p>>1): slot q_phys = (q + (p>>1)) & 3 (spreads write banks;
  // phase 3 un-rotates).
  {
    const int ic0 = h * 6 + (i0 >> 4);
    const int p0w = i0 & 15;
    const int i1 = i0 + 1;
    const int ic1 = h * 6 + (i1 >> 4);
    const int p1w = i1 & 15;
    #pragma unroll
    for (int n4 = 0; n4 < 4; ++n4) {
      const int q0 = (n4 + (p0w >> 1)) & 3;
      const int q1 = (n4 + (p1w >> 1)) & 3;
      *(float4*)(smem + ic0 * 256 + p0w * 16 + q0 * 4) = r0[n4];
      *(float4*)(smem + ic1 * 256 + p1w * 16 + q1 * 4) = r1[n4];
    }
  }
  __syncthreads();

  // phase 3: proj 1x1: thread owns one output pixel across 48 channels
  if (t < 256) {
    const int xl = t & 63, ph = t >> 6;
    const int p  = ph * 4 + (xl & 3);
    const int wwl = xl >> 2;
    const int qp = ((wwl >> 2) + (p >> 1)) & 3;       // un-rotate
    const int wwp = qp * 4 + (wwl & 3);
    float sv[48];
    #pragma unroll
    for (int ic = 0; ic < 48; ++ic) sv[ic] = smem[ic * 256 + p * 16 + wwp];
    const int H = hh * 4 + ph;
    const int Wp = wg * 64 + xl;
    float* outp = out + ((size_t)b * 48 << SHIFT_HW) + (H << 9) + Wp;
    #pragma unroll 1
    for (int oc = 0; oc < 48; oc += 2) {
      float acc0 = 0.f, acc1 = 0.f;
      #pragma unroll
      for (int ic = 0; ic < 48; ++ic) {
        acc0 += pw[oc * 48 + ic]       * sv[ic];   // uniform -> s_loads
        acc1 += pw[(oc + 1) * 48 + ic] * sv[ic];
      }
      outp[(size_t)oc << SHIFT_HW]       = acc0;
      outp[(size_t)(oc + 1) << SHIFT_HW] = acc1;
    }
  }
}

// ---------------------------------------------------------------------------
extern "C" void kernel_launch(void* const* d_in, const int* in_sizes, int n_in,
                              void* d_out, int out_size, void* d_ws, size_t ws_size,
                              hipStream_t stream) {
  const float* x      = (const float*)d_in[0];
  const float* qkv_w  = (const float*)d_in[1];
  const float* dw_w   = (const float*)d_in[2];
  const float* proj_w = (const float*)d_in[3];
  const float* temp   = (const float*)d_in[4];
  float* ws = (float*)d_ws;
  float* qb = ws + QB_OFF;
  float* kb = ws + KB_OFF;
  float* vb = ws + VB_OFF;
  float* sq = ws + SQ_OFF;
  float* sk = ws + SK_OFF;
  float* A  = ws + A_OFF;
  // partial-G scratch lives in d_out (18.9 MB needed, 50.3 MB available);
  // K5 fully overwrites d_out afterwards.
  float* Gp = (float*)d_out;

  // zero sq + sk only (G atomics are gone)
  hipMemsetAsync(sq, 0, (size_t)3072 * sizeof(float), stream);

  k1_qkv_dw<<<dim3(32, 32, 2), 384, 0, stream>>>(x, qkv_w, dw_w, qb, kb, vb);
  k3_gram<<<dim3(32, 16), 256, 0, stream>>>(qb, kb, Gp, sq, sk);
  k4_softmax<<<dim3(96, 16), 128, 0, stream>>>(Gp, sq, sk, temp, A);
  k5_av_proj<<<2048, 384, 0, stream>>>(vb, A, proj_w, (float*)d_out);
}